// Round 5
// baseline (1376.030 us; speedup 1.0000x reference)
//
#include <hip/hip_runtime.h>
#include <hip/hip_bf16.h>

#define B_ 16
#define S_ 256
#define D_ 256
#define H_ 128
#define K_ 64
#define SIN 512
#define F4H 512

typedef __hip_bfloat16 bf16;

__device__ __forceinline__ float bf2f(bf16 h) { return __bfloat162float(h); }
__device__ __forceinline__ float fast_sigmoid(float x) {
  return 1.0f / (1.0f + __expf(-x));
}
__device__ __forceinline__ float fast_tanh(float x) {
  return 1.0f - 2.0f / (__expf(2.0f * x) + 1.0f);
}

// dtype sniff: flag=1 if float tensors are f32 on device, 0 if bf16
__global__ __launch_bounds__(256) void k_sniff(const unsigned short* __restrict__ xs,
                                               int* __restrict__ flag) {
  __shared__ int cnt;
  if (threadIdx.x == 0) cnt = 0;
  __syncthreads();
  int c = 0;
  for (int i = threadIdx.x; i < 8192; i += 256) {
    int e = (xs[i] >> 7) & 0xFF;
    c += (e == 0 || e == 0xFF);
  }
  if (c) atomicAdd(&cnt, c);
  __syncthreads();
  if (threadIdx.x == 0) *flag = (cnt > 0) ? 1 : 0;
}

// actions decode: int32 vs int64 autodetect; status=1 iff all decoded in [0,8)
__global__ void k_act(const int* __restrict__ a, int* __restrict__ act_out,
                      int* __restrict__ status) {
  if (threadIdx.x == 0 && blockIdx.x == 0) {
    bool oddzero = true;
    for (int i = 1; i < 16; i += 2) oddzero = oddzero && (a[i] == 0);
    bool ok = true;
    for (int b = 0; b < 16; ++b) {
      int v = oddzero ? a[2 * b] : a[b];
      act_out[b] = (v < 0) ? 0 : (v > 7 ? 7 : v);
      ok = ok && (v >= 0 && v < 8);
    }
    *status = ok ? 1 : 0;
  }
}

__global__ __launch_bounds__(256) void k_cvt(const void* __restrict__ src,
    float* __restrict__ dst, int n, const int* __restrict__ flag) {
  int i = blockIdx.x * 256 + threadIdx.x;
  if (i >= n) return;
  dst[i] = (*flag) ? ((const float*)src)[i] : bf2f(((const bf16*)src)[i]);
}

// x[b][s][d] -> x0[(s*16+b)*256+d]
__global__ __launch_bounds__(256) void k_cvt_x(const void* __restrict__ src,
    float* __restrict__ x0, const int* __restrict__ flag) {
  int idx = blockIdx.x * 256 + threadIdx.x;
  int d = idx & 255, s = (idx >> 8) & 255, b = idx >> 16;
  float v = (*flag) ? ((const float*)src)[idx] : bf2f(((const bf16*)src)[idx]);
  x0[(((s << 4) + b) << 8) + d] = v;
}

// xt[(b*256+l)*64+k] = b1[a][k] + sum_d x0[(l*16+b)][d]*w1[a][d][k]
__global__ __launch_bounds__(256) void k_xt(const float* __restrict__ x0,
    const int* __restrict__ act, const float* __restrict__ w1,
    const float* __restrict__ b1, float* __restrict__ xt) {
  int idx = blockIdx.x * 256 + threadIdx.x;   // 262144
  int k = idx & 63, rr = idx >> 6;            // rr = b*256+l
  int b = rr >> 8, l = rr & 255;
  int a = act[b];
  const float* xr = x0 + (((l << 4) + b) << 8);
  const float* w = w1 + a * (D_ * K_) + k;
  float acc = b1[a * K_ + k];
#pragma unroll 8
  for (int d = 0; d < D_; ++d) acc += xr[d] * w[d * K_];
  xt[idx] = acc;
}

// yt[(s*16+b)*64+k] = b2[a][k] + sum_d cur[row][d]*w2[a][d][k]
__global__ __launch_bounds__(256) void k_yt(const float* __restrict__ cur,
    const int* __restrict__ act, const float* __restrict__ w2,
    const float* __restrict__ b2, float* __restrict__ yt) {
  int idx = blockIdx.x * 256 + threadIdx.x;
  int k = idx & 63, row = idx >> 6;           // row = s*16+b
  int b = row & 15;
  int a = act[b];
  const float* xr = cur + row * D_;
  const float* w = w2 + a * (D_ * K_) + k;
  float acc = b2[a * K_ + k];
#pragma unroll 8
  for (int d = 0; d < D_; ++d) acc += xr[d] * w[d * K_];
  yt[idx] = acc;
}

// scores[row*256+l] = sum_k va[k]*tanh(xt[b,l,k]+yt[row,k])
__global__ __launch_bounds__(256) void k_score(const float* __restrict__ xt,
    const float* __restrict__ yt, const float* __restrict__ v,
    const int* __restrict__ act, const unsigned char* __restrict__ xmask,
    float* __restrict__ scores) {
  int idx = blockIdx.x * 256 + threadIdx.x;   // 1048576
  int l = idx & 255, row = idx >> 8;
  int b = row & 15;
  int a = act[b];
  const float* xr = xt + (b * 256 + l) * K_;
  const float* yr = yt + row * K_;
  const float* vr = v + a * K_;
  float acc = 0.f;
#pragma unroll 8
  for (int k = 0; k < K_; ++k) acc += vr[k] * fast_tanh(xr[k] + yr[k]);
  if (xmask[b * S_ + l]) acc = -1e30f;
  scores[idx] = acc;
}

// softmax over l per row (block = row)
__global__ __launch_bounds__(256) void k_softmax(float* __restrict__ scores) {
  __shared__ float buf[256];
  int tid = threadIdx.x;
  int row = blockIdx.x;
  float sval = scores[row * 256 + tid];
  buf[tid] = sval;
  __syncthreads();
  for (int st = 128; st; st >>= 1) {
    if (tid < st) buf[tid] = fmaxf(buf[tid], buf[tid + st]);
    __syncthreads();
  }
  float m = buf[0];
  __syncthreads();
  float p = __expf(sval - m);
  buf[tid] = p;
  __syncthreads();
  for (int st = 128; st; st >>= 1) {
    if (tid < st) buf[tid] += buf[tid + st];
    __syncthreads();
  }
  float ssum = buf[0];
  scores[row * 256 + tid] = p / ssum;
}

// pools + inputs assembly: inputs[row] = [cur(row) | sum_l sc*x0]
__global__ __launch_bounds__(256) void k_pool(const float* __restrict__ scores,
    const float* __restrict__ x0, const float* __restrict__ cur,
    float* __restrict__ inputs) {
  int idx = blockIdx.x * 256 + threadIdx.x;   // 1048576
  int d = idx & 255, row = idx >> 8;
  int b = row & 15;
  const float* sc = scores + row * 256;
  const float* xb = x0 + b * D_ + d;          // x0[(l*16+b)*256+d] = xb[l*4096]
  float acc = 0.f;
#pragma unroll 4
  for (int l = 0; l < 256; ++l) acc += sc[l] * xb[l * 4096];
  inputs[row * SIN + 256 + d] = acc;
  inputs[row * SIN + d] = cur[row * D_ + d];
}

// U[row][col] = sum_k inputs[row][k]*W[k][col] ; blockIdx.y = dir
__global__ __launch_bounds__(256) void k_gemm(const float* __restrict__ A,
    const float* __restrict__ Wf, const float* __restrict__ Wb,
    float* __restrict__ Uf, float* __restrict__ Ub) {
  int idx = blockIdx.x * 256 + threadIdx.x;   // 2097152
  int col = idx & 511, row = idx >> 9;
  const float* W = blockIdx.y ? Wb : Wf;
  float* U = blockIdx.y ? Ub : Uf;
  const float* ar = A + row * SIN;
  float acc = 0.f;
#pragma unroll 8
  for (int k = 0; k < SIN; ++k) acc += ar[k] * W[k * F4H + col];
  U[row * F4H + col] = acc;
}

// SRU recurrence; BOTH directions scan forward (exactly as the reference's lax.scan)
__global__ __launch_bounds__(256) void k_scan(const float* __restrict__ Uf,
    const float* __restrict__ Ub, const float* __restrict__ bfp,
    const float* __restrict__ bbp, float* __restrict__ next) {
  int gid = blockIdx.x * 256 + threadIdx.x;   // 4096
  int dir = gid >> 11;
  int rem = gid & 2047;
  int b = rem >> 7;
  int h = rem & 127;
  const float* U = dir ? Ub : Uf;
  const float* bias = dir ? bbp : bfp;
  float bfv = bias[h];
  float brv = bias[128 + h];
  float c = 0.f;
  float* op = next + b * 256 + dir * 128 + h;
  const float* up = U + b * 512 + h;
  for (int s = 0; s < 256; ++s) {
    const float* q = up + s * (16 * 512);
    float u0 = q[0], uf = q[128], ur = q[256], hw = q[384];
    float f = fast_sigmoid(uf + bfv);
    float r = fast_sigmoid(ur + brv);
    c = f * (c - u0) + u0;
    float hv = r * fast_tanh(c) + (1.f - r) * hw;
    op[s * (16 * 256)] = hv;
  }
}

// out[b][s][d] = f32 cur[(s*16+b)*256+d]; status==0 -> sentinel 20.0
__global__ __launch_bounds__(256) void k_out(const float* __restrict__ cur,
    const int* __restrict__ status, float* __restrict__ out) {
  int idx = blockIdx.x * 256 + threadIdx.x;
  int d = idx & 255;
  int s = (idx >> 8) & 255;
  int b = idx >> 16;
  float val = (*status) ? cur[(((s << 4) + b) << 8) + d] : 20.0f;
  out[idx] = val;
}

__global__ __launch_bounds__(256) void k_fill(float* out, float v, int n) {
  int idx = blockIdx.x * 256 + threadIdx.x;
  if (idx < n) out[idx] = v;
}

extern "C" void kernel_launch(void* const* d_in, const int* in_sizes, int n_in,
                              void* d_out, int out_size, void* d_ws, size_t ws_size,
                              hipStream_t stream) {
  float* out = (float*)d_out;
  int fill_grid = (out_size + 255) / 256;

  // env validation: sentinel 10.0 on mismatch
  const int exp_sizes[12] = {1048576, 4096, 16, 131072, 512, 131072, 512, 512,
                             524288, 512, 524288, 512};
  bool env_ok = (n_in == 12);
  if (env_ok)
    for (int i = 0; i < 12; ++i) env_ok = env_ok && (in_sizes[i] == exp_sizes[i]);
  if (!env_ok) {
    k_fill<<<fill_grid, 256, 0, stream>>>(out, 10.0f, out_size);
    return;
  }

  // ws layout (f32 elements)
  float* ws = (float*)d_ws;
  size_t off = 0;
  float* x0     = ws + off; off += 1048576;
  float* pb0    = ws + off; off += 1048576;
  float* pb1    = ws + off; off += 1048576;
  float* xt     = ws + off; off += 262144;
  float* yt     = ws + off; off += 262144;
  float* scores = ws + off; off += 1048576;
  float* inputs = ws + off; off += 2097152;
  float* Uf     = ws + off; off += 2097152;
  float* Ub     = ws + off; off += 2097152;
  float* w1f    = ws + off; off += 131072;
  float* w2f    = ws + off; off += 131072;
  float* b1f    = ws + off; off += 512;
  float* b2f    = ws + off; off += 512;
  float* vf     = ws + off; off += 512;
  float* swff   = ws + off; off += 524288;
  float* swbf   = ws + off; off += 524288;
  float* sbff   = ws + off; off += 512;
  float* sbbf   = ws + off; off += 512;
  int*   flag   = (int*)(ws + off); off += 16;
  int*   act    = (int*)(ws + off); off += 16;
  int*   status = (int*)(ws + off); off += 16;

  if (ws_size < off * sizeof(float)) {   // sentinel 30.0: scratch too small
    k_fill<<<fill_grid, 256, 0, stream>>>(out, 30.0f, out_size);
    return;
  }

  k_sniff<<<1, 256, 0, stream>>>((const unsigned short*)d_in[0], flag);
  k_act<<<1, 64, 0, stream>>>((const int*)d_in[2], act, status);

  k_cvt_x<<<4096, 256, 0, stream>>>(d_in[0], x0, flag);
  k_cvt<<<512, 256, 0, stream>>>(d_in[3], w1f, 131072, flag);
  k_cvt<<<2, 256, 0, stream>>>(d_in[4], b1f, 512, flag);
  k_cvt<<<512, 256, 0, stream>>>(d_in[5], w2f, 131072, flag);
  k_cvt<<<2, 256, 0, stream>>>(d_in[6], b2f, 512, flag);
  k_cvt<<<2, 256, 0, stream>>>(d_in[7], vf, 512, flag);
  k_cvt<<<2048, 256, 0, stream>>>(d_in[8], swff, 524288, flag);
  k_cvt<<<2, 256, 0, stream>>>(d_in[9], sbff, 512, flag);
  k_cvt<<<2048, 256, 0, stream>>>(d_in[10], swbf, 524288, flag);
  k_cvt<<<2, 256, 0, stream>>>(d_in[11], sbbf, 512, flag);

  k_xt<<<1024, 256, 0, stream>>>(x0, act, w1f, b1f, xt);

  const unsigned char* xmask = (const unsigned char*)d_in[1];
  float* cur = x0;
  float* nxt = pb0;
  for (int layer = 0; layer < 2; ++layer) {
    k_yt<<<1024, 256, 0, stream>>>(cur, act, w2f, b2f, yt);
    k_score<<<4096, 256, 0, stream>>>(xt, yt, vf, act, xmask, scores);
    k_softmax<<<4096, 256, 0, stream>>>(scores);
    k_pool<<<4096, 256, 0, stream>>>(scores, x0, cur, inputs);
    k_gemm<<<dim3(8192, 2), 256, 0, stream>>>(inputs,
        swff + layer * SIN * F4H, swbf + layer * SIN * F4H, Uf, Ub);
    k_scan<<<16, 256, 0, stream>>>(Uf, Ub, sbff + layer * 256, sbbf + layer * 256, nxt);
    cur = nxt;
    nxt = (layer == 0) ? pb1 : pb0;
  }
  k_out<<<4096, 256, 0, stream>>>(cur, status, out);
}

// Round 6
// 494.408 us; speedup vs baseline: 2.7832x; 2.7832x over previous
//
#include <hip/hip_runtime.h>
#include <hip/hip_bf16.h>

#define B_ 16
#define S_ 256
#define D_ 256
#define H_ 128
#define K_ 64
#define SIN 512
#define F4H 512

__device__ __forceinline__ float fast_sigmoid(float x) {
  return 1.0f / (1.0f + __expf(-x));
}
__device__ __forceinline__ float fast_tanh(float x) {
  return 1.0f - 2.0f / (__expf(2.0f * x) + 1.0f);
}

// actions decode: int32 vs int64 autodetect; status=1 iff all decoded in [0,8)
__global__ void k_act(const int* __restrict__ a, int* __restrict__ act_out,
                      int* __restrict__ status) {
  if (threadIdx.x == 0 && blockIdx.x == 0) {
    bool oddzero = true;
    for (int i = 1; i < 16; i += 2) oddzero = oddzero && (a[i] == 0);
    bool ok = true;
    for (int b = 0; b < 16; ++b) {
      int v = oddzero ? a[2 * b] : a[b];
      act_out[b] = (v < 0) ? 0 : (v > 7 ? 7 : v);
      ok = ok && (v >= 0 && v < 8);
    }
    *status = ok ? 1 : 0;
  }
}

// x[b][s][d] -> x0[(s*16+b)*256+d]   (inputs proven f32 on device)
__global__ __launch_bounds__(256) void k_cvt_x(const float* __restrict__ src,
    float* __restrict__ x0) {
  int idx = blockIdx.x * 256 + threadIdx.x;
  int d = idx & 255, s = (idx >> 8) & 255, b = idx >> 16;
  x0[(((s << 4) + b) << 8) + d] = src[idx];
}

// xt[(b*256+l)*64+k] = b1[a][k] + sum_d x0[(l*16+b)][d]*w1[a][d][k]
__global__ __launch_bounds__(256) void k_xt(const float* __restrict__ x0,
    const int* __restrict__ act, const float* __restrict__ w1,
    const float* __restrict__ b1, float* __restrict__ xt) {
  int idx = blockIdx.x * 256 + threadIdx.x;   // 262144
  int k = idx & 63, rr = idx >> 6;            // rr = b*256+l
  int b = rr >> 8, l = rr & 255;
  int a = act[b];
  const float* xr = x0 + (((l << 4) + b) << 8);
  const float* w = w1 + a * (D_ * K_) + k;
  float acc = b1[a * K_ + k];
#pragma unroll 8
  for (int d = 0; d < D_; ++d) acc += xr[d] * w[d * K_];
  xt[idx] = acc;
}

// yt[(s*16+b)*64+k] = b2[a][k] + sum_d cur[row][d]*w2[a][d][k]
__global__ __launch_bounds__(256) void k_yt(const float* __restrict__ cur,
    const int* __restrict__ act, const float* __restrict__ w2,
    const float* __restrict__ b2, float* __restrict__ yt) {
  int idx = blockIdx.x * 256 + threadIdx.x;
  int k = idx & 63, row = idx >> 6;           // row = s*16+b
  int b = row & 15;
  int a = act[b];
  const float* xr = cur + row * D_;
  const float* w = w2 + a * (D_ * K_) + k;
  float acc = b2[a * K_ + k];
#pragma unroll 8
  for (int d = 0; d < D_; ++d) acc += xr[d] * w[d * K_];
  yt[idx] = acc;
}

// fused per-row attention: scores(tanh) -> softmax -> pools -> inputs=[cur|pools]
__global__ __launch_bounds__(256) void k_attn(const float* __restrict__ xt,
    const float* __restrict__ yt, const float* __restrict__ v,
    const int* __restrict__ act, const unsigned char* __restrict__ xmask,
    const float* __restrict__ x0, const float* __restrict__ cur,
    float* __restrict__ inputs) {
  __shared__ float yts[K_], vas[K_];
  __shared__ float sc[256], buf[256];
  int tid = threadIdx.x;
  int row = blockIdx.x;          // s*16+b
  int b = row & 15;
  if (tid < K_) {
    yts[tid] = yt[row * K_ + tid];
    vas[tid] = v[act[b] * K_ + tid];
  }
  __syncthreads();
  // scores: l = tid
  {
    const float4* xr = (const float4*)(xt + (b * 256 + tid) * K_);
    const float4* yr = (const float4*)yts;
    const float4* vr = (const float4*)vas;
    float acc = 0.f;
#pragma unroll
    for (int q = 0; q < 16; ++q) {
      float4 xv = xr[q], yv = yr[q], vv = vr[q];
      acc += vv.x * fast_tanh(xv.x + yv.x);
      acc += vv.y * fast_tanh(xv.y + yv.y);
      acc += vv.z * fast_tanh(xv.z + yv.z);
      acc += vv.w * fast_tanh(xv.w + yv.w);
    }
    if (xmask[b * S_ + tid]) acc = -1e30f;
    sc[tid] = acc;
    buf[tid] = acc;
  }
  __syncthreads();
  // softmax (validated tree pattern)
  for (int st = 128; st; st >>= 1) {
    if (tid < st) buf[tid] = fmaxf(buf[tid], buf[tid + st]);
    __syncthreads();
  }
  float m = buf[0];
  __syncthreads();
  float p = __expf(sc[tid] - m);
  buf[tid] = p;
  __syncthreads();
  for (int st = 128; st; st >>= 1) {
    if (tid < st) buf[tid] += buf[tid + st];
    __syncthreads();
  }
  float ssum = buf[0];
  __syncthreads();
  sc[tid] = p / ssum;
  __syncthreads();
  // pools: d = tid ; inputs = [cur | pools]
  float acc = 0.f;
  const float* xb = x0 + b * D_ + tid;        // x0[(l*16+b)*256+d] = xb[l*4096]
#pragma unroll 4
  for (int l = 0; l < 256; ++l) acc += sc[l] * xb[l * 4096];
  inputs[row * SIN + 256 + tid] = acc;
  inputs[row * SIN + tid] = cur[row * D_ + tid];
}

// tiled f32 GEMM: U(dir) = inputs(4096x512) @ W(dir)(512x512)
// 64x64 tile, BK=16, 256 threads, 4x4 acc/thread
__global__ __launch_bounds__(256) void k_gemm(const float* __restrict__ A,
    const float* __restrict__ Wf, const float* __restrict__ Wb,
    float* __restrict__ Uf, float* __restrict__ Ub) {
  __shared__ float As[16][65];   // [k][m]
  __shared__ float Bs[16][68];   // [k][n]
  const float* W = blockIdx.z ? Wb : Wf;
  float* U = blockIdx.z ? Ub : Uf;
  int tid = threadIdx.x;
  int tx = tid & 15, ty = tid >> 4;
  int bm = blockIdx.x * 64, bn = blockIdx.y * 64;
  int am = tid >> 2, ak = (tid & 3) << 2;
  float acc[4][4] = {};
  for (int kk = 0; kk < 512; kk += 16) {
    float4 av = *(const float4*)(A + (bm + am) * SIN + kk + ak);
    As[ak + 0][am] = av.x;
    As[ak + 1][am] = av.y;
    As[ak + 2][am] = av.z;
    As[ak + 3][am] = av.w;
    float4 bv = *(const float4*)(W + (kk + ty) * F4H + bn + (tx << 2));
    *(float4*)&Bs[ty][tx << 2] = bv;
    __syncthreads();
#pragma unroll
    for (int k = 0; k < 16; ++k) {
      float a0 = As[k][(ty << 2) + 0];
      float a1 = As[k][(ty << 2) + 1];
      float a2 = As[k][(ty << 2) + 2];
      float a3 = As[k][(ty << 2) + 3];
      float b0 = Bs[k][(tx << 2) + 0];
      float b1 = Bs[k][(tx << 2) + 1];
      float b2 = Bs[k][(tx << 2) + 2];
      float b3 = Bs[k][(tx << 2) + 3];
      acc[0][0] += a0 * b0; acc[0][1] += a0 * b1; acc[0][2] += a0 * b2; acc[0][3] += a0 * b3;
      acc[1][0] += a1 * b0; acc[1][1] += a1 * b1; acc[1][2] += a1 * b2; acc[1][3] += a1 * b3;
      acc[2][0] += a2 * b0; acc[2][1] += a2 * b1; acc[2][2] += a2 * b2; acc[2][3] += a2 * b3;
      acc[3][0] += a3 * b0; acc[3][1] += a3 * b1; acc[3][2] += a3 * b2; acc[3][3] += a3 * b3;
    }
    __syncthreads();
  }
#pragma unroll
  for (int i = 0; i < 4; ++i) {
    float4 o = make_float4(acc[i][0], acc[i][1], acc[i][2], acc[i][3]);
    *(float4*)(U + (bm + (ty << 2) + i) * F4H + bn + (tx << 2)) = o;
  }
}

// SRU recurrence; BOTH directions scan forward (matches reference lax.scan)
__global__ __launch_bounds__(256) void k_scan(const float* __restrict__ Uf,
    const float* __restrict__ Ub, const float* __restrict__ bfp,
    const float* __restrict__ bbp, float* __restrict__ next) {
  int gid = blockIdx.x * 256 + threadIdx.x;   // 4096
  int dir = gid >> 11;
  int rem = gid & 2047;
  int b = rem >> 7;
  int h = rem & 127;
  const float* U = dir ? Ub : Uf;
  const float* bias = dir ? bbp : bfp;
  float bfv = bias[h];
  float brv = bias[128 + h];
  float c = 0.f;
  float* op = next + b * 256 + dir * 128 + h;
  const float* up = U + b * 512 + h;
  for (int s = 0; s < 256; ++s) {
    const float* q = up + s * (16 * 512);
    float u0 = q[0], uf = q[128], ur = q[256], hw = q[384];
    float f = fast_sigmoid(uf + bfv);
    float r = fast_sigmoid(ur + brv);
    c = f * (c - u0) + u0;
    float hv = r * fast_tanh(c) + (1.f - r) * hw;
    op[s * (16 * 256)] = hv;
  }
}

// out[b][s][d] = cur[(s*16+b)*256+d]; status==0 -> sentinel 20.0
__global__ __launch_bounds__(256) void k_out(const float* __restrict__ cur,
    const int* __restrict__ status, float* __restrict__ out) {
  int idx = blockIdx.x * 256 + threadIdx.x;
  int d = idx & 255;
  int s = (idx >> 8) & 255;
  int b = idx >> 16;
  out[idx] = (*status) ? cur[(((s << 4) + b) << 8) + d] : 20.0f;
}

__global__ __launch_bounds__(256) void k_fill(float* out, float v, int n) {
  int idx = blockIdx.x * 256 + threadIdx.x;
  if (idx < n) out[idx] = v;
}

extern "C" void kernel_launch(void* const* d_in, const int* in_sizes, int n_in,
                              void* d_out, int out_size, void* d_ws, size_t ws_size,
                              hipStream_t stream) {
  float* out = (float*)d_out;
  int fill_grid = (out_size + 255) / 256;

  const int exp_sizes[12] = {1048576, 4096, 16, 131072, 512, 131072, 512, 512,
                             524288, 512, 524288, 512};
  bool env_ok = (n_in == 12);
  if (env_ok)
    for (int i = 0; i < 12; ++i) env_ok = env_ok && (in_sizes[i] == exp_sizes[i]);
  if (!env_ok) {
    k_fill<<<fill_grid, 256, 0, stream>>>(out, 10.0f, out_size);
    return;
  }

  // inputs proven f32 on device (r1: bf16-read -> NaN; r2+: f32-read -> finite)
  const float* x    = (const float*)d_in[0];
  const unsigned char* xmask = (const unsigned char*)d_in[1];
  const float* w1   = (const float*)d_in[3];
  const float* b1   = (const float*)d_in[4];
  const float* w2   = (const float*)d_in[5];
  const float* b2   = (const float*)d_in[6];
  const float* v    = (const float*)d_in[7];
  const float* sw_f = (const float*)d_in[8];
  const float* sb_f = (const float*)d_in[9];
  const float* sw_b = (const float*)d_in[10];
  const float* sb_b = (const float*)d_in[11];

  // ws layout (f32 elements)
  float* ws = (float*)d_ws;
  size_t off = 0;
  float* x0     = ws + off; off += 1048576;
  float* pb0    = ws + off; off += 1048576;
  float* pb1    = ws + off; off += 1048576;
  float* xt     = ws + off; off += 262144;
  float* yt     = ws + off; off += 262144;
  float* inputs = ws + off; off += 2097152;
  float* Uf     = ws + off; off += 2097152;
  float* Ub     = ws + off; off += 2097152;
  int*   act    = (int*)(ws + off); off += 16;
  int*   status = (int*)(ws + off); off += 16;

  if (ws_size < off * sizeof(float)) {
    k_fill<<<fill_grid, 256, 0, stream>>>(out, 30.0f, out_size);
    return;
  }

  k_act<<<1, 64, 0, stream>>>((const int*)d_in[2], act, status);
  k_cvt_x<<<4096, 256, 0, stream>>>(x, x0);
  k_xt<<<1024, 256, 0, stream>>>(x0, act, w1, b1, xt);

  float* cur = x0;
  float* nxt = pb0;
  for (int layer = 0; layer < 2; ++layer) {
    k_yt<<<1024, 256, 0, stream>>>(cur, act, w2, b2, yt);
    k_attn<<<4096, 256, 0, stream>>>(xt, yt, v, act, xmask, x0, cur, inputs);
    k_gemm<<<dim3(64, 8, 2), 256, 0, stream>>>(inputs,
        sw_f + layer * SIN * F4H, sw_b + layer * SIN * F4H, Uf, Ub);
    k_scan<<<16, 256, 0, stream>>>(Uf, Ub, sb_f + layer * 256, sb_b + layer * 256, nxt);
    cur = nxt;
    nxt = (layer == 0) ? pb1 : pb0;
  }
  k_out<<<4096, 256, 0, stream>>>(cur, status, out);
}

// Round 7
// 329.744 us; speedup vs baseline: 4.1730x; 1.4994x over previous
//
#include <hip/hip_runtime.h>
#include <hip/hip_bf16.h>

#define S_ 256
#define D_ 256
#define K_ 64
#define SIN 512
#define F4H 512

typedef unsigned short u16;
typedef __attribute__((ext_vector_type(8))) short short8;
typedef __attribute__((ext_vector_type(4))) float f32x4;

__device__ __forceinline__ float fast_sigmoid(float x) {
  return 1.0f / (1.0f + __expf(-x));
}
__device__ __forceinline__ float fast_tanh(float x) {
  return 1.0f - 2.0f / (__expf(2.0f * x) + 1.0f);
}
__device__ __forceinline__ u16 f2bf(float f) {   // RNE f32->bf16
  unsigned int u = __float_as_uint(f);
  return (u16)((u + 0x7fff + ((u >> 16) & 1)) >> 16);
}

// actions decode: int32 vs int64 autodetect; status=1 iff all in [0,8)
__global__ void k_act(const int* __restrict__ a, int* __restrict__ act_out,
                      int* __restrict__ status) {
  if (threadIdx.x == 0 && blockIdx.x == 0) {
    bool oddzero = true;
    for (int i = 1; i < 16; i += 2) oddzero = oddzero && (a[i] == 0);
    bool ok = true;
    for (int b = 0; b < 16; ++b) {
      int v = oddzero ? a[2 * b] : a[b];
      act_out[b] = (v < 0) ? 0 : (v > 7 ? 7 : v);
      ok = ok && (v >= 0 && v < 8);
    }
    *status = ok ? 1 : 0;
  }
}

// SRU weights f32 -> bf16, transposed to [layer*2+dir][n][k] (k contiguous)
__global__ __launch_bounds__(256) void k_prep(const float* __restrict__ sw_f,
    const float* __restrict__ sw_b, u16* __restrict__ wt) {
  int idx = blockIdx.x * 256 + threadIdx.x;   // 4*512*512
  int m = idx >> 18;
  int rem = idx & 262143;
  int n = rem >> 9, kd = rem & 511;
  int layer = m >> 1;
  const float* src = (m & 1) ? sw_b : sw_f;
  wt[idx] = f2bf(src[layer * 262144 + kd * 512 + n]);
}

// tiled: xt[(b*256+l)*64+n] = b1[a][n] + sum_d x[b][l][d]*w1[a][d][n]
__global__ __launch_bounds__(256) void k_xt(const float* __restrict__ x,
    const int* __restrict__ act, const float* __restrict__ w1,
    const float* __restrict__ b1, float* __restrict__ xt) {
  __shared__ float As[16][65], Bs[16][68];
  int b = blockIdx.y;
  int a = act[b];
  int l0 = blockIdx.x * 64;
  const float* A = x + b * (S_ * D_);
  const float* W = w1 + a * (D_ * K_);
  int tid = threadIdx.x;
  int tx = tid & 15, ty = tid >> 4;
  int am = tid >> 2, ak = (tid & 3) << 2;
  float acc[4][4] = {};
  for (int kk = 0; kk < D_; kk += 16) {
    float4 av = *(const float4*)(A + (l0 + am) * D_ + kk + ak);
    As[ak + 0][am] = av.x; As[ak + 1][am] = av.y;
    As[ak + 2][am] = av.z; As[ak + 3][am] = av.w;
    float4 bv = *(const float4*)(W + (kk + ty) * K_ + (tx << 2));
    *(float4*)&Bs[ty][tx << 2] = bv;
    __syncthreads();
#pragma unroll
    for (int k = 0; k < 16; ++k) {
      float a0 = As[k][(ty << 2) + 0], a1 = As[k][(ty << 2) + 1];
      float a2 = As[k][(ty << 2) + 2], a3 = As[k][(ty << 2) + 3];
      float b0 = Bs[k][(tx << 2) + 0], b1v = Bs[k][(tx << 2) + 1];
      float b2v = Bs[k][(tx << 2) + 2], b3v = Bs[k][(tx << 2) + 3];
      acc[0][0] += a0 * b0; acc[0][1] += a0 * b1v; acc[0][2] += a0 * b2v; acc[0][3] += a0 * b3v;
      acc[1][0] += a1 * b0; acc[1][1] += a1 * b1v; acc[1][2] += a1 * b2v; acc[1][3] += a1 * b3v;
      acc[2][0] += a2 * b0; acc[2][1] += a2 * b1v; acc[2][2] += a2 * b2v; acc[2][3] += a2 * b3v;
      acc[3][0] += a3 * b0; acc[3][1] += a3 * b1v; acc[3][2] += a3 * b2v; acc[3][3] += a3 * b3v;
    }
    __syncthreads();
  }
  float4 bias = *(const float4*)(b1 + a * K_ + (tx << 2));
#pragma unroll
  for (int i = 0; i < 4; ++i) {
    float4 o = make_float4(acc[i][0] + bias.x, acc[i][1] + bias.y,
                           acc[i][2] + bias.z, acc[i][3] + bias.w);
    *(float4*)(xt + (b * 256 + l0 + (ty << 2) + i) * K_ + (tx << 2)) = o;
  }
}

// tiled: yt[((s0+m)*16+b)*64+n] = b2[a][n] + sum_d cur[s][d]*w2[a][d][n]
// cur row s of batch b at curb + b*bstride + s*sstride
__global__ __launch_bounds__(256) void k_yt(const float* __restrict__ curb,
    int sstride, int bstride, const int* __restrict__ act,
    const float* __restrict__ w2, const float* __restrict__ b2,
    float* __restrict__ yt) {
  __shared__ float As[16][65], Bs[16][68];
  int b = blockIdx.y;
  int a = act[b];
  int s0 = blockIdx.x * 64;
  const float* A = curb + b * bstride;
  const float* W = w2 + a * (D_ * K_);
  int tid = threadIdx.x;
  int tx = tid & 15, ty = tid >> 4;
  int am = tid >> 2, ak = (tid & 3) << 2;
  float acc[4][4] = {};
  for (int kk = 0; kk < D_; kk += 16) {
    float4 av = *(const float4*)(A + (s0 + am) * sstride + kk + ak);
    As[ak + 0][am] = av.x; As[ak + 1][am] = av.y;
    As[ak + 2][am] = av.z; As[ak + 3][am] = av.w;
    float4 bv = *(const float4*)(W + (kk + ty) * K_ + (tx << 2));
    *(float4*)&Bs[ty][tx << 2] = bv;
    __syncthreads();
#pragma unroll
    for (int k = 0; k < 16; ++k) {
      float a0 = As[k][(ty << 2) + 0], a1 = As[k][(ty << 2) + 1];
      float a2 = As[k][(ty << 2) + 2], a3 = As[k][(ty << 2) + 3];
      float b0 = Bs[k][(tx << 2) + 0], b1v = Bs[k][(tx << 2) + 1];
      float b2v = Bs[k][(tx << 2) + 2], b3v = Bs[k][(tx << 2) + 3];
      acc[0][0] += a0 * b0; acc[0][1] += a0 * b1v; acc[0][2] += a0 * b2v; acc[0][3] += a0 * b3v;
      acc[1][0] += a1 * b0; acc[1][1] += a1 * b1v; acc[1][2] += a1 * b2v; acc[1][3] += a1 * b3v;
      acc[2][0] += a2 * b0; acc[2][1] += a2 * b1v; acc[2][2] += a2 * b2v; acc[2][3] += a2 * b3v;
      acc[3][0] += a3 * b0; acc[3][1] += a3 * b1v; acc[3][2] += a3 * b2v; acc[3][3] += a3 * b3v;
    }
    __syncthreads();
  }
  float4 bias = *(const float4*)(b2 + a * K_ + (tx << 2));
#pragma unroll
  for (int i = 0; i < 4; ++i) {
    float4 o = make_float4(acc[i][0] + bias.x, acc[i][1] + bias.y,
                           acc[i][2] + bias.z, acc[i][3] + bias.w);
    *(float4*)(yt + ((s0 + (ty << 2) + i) * 16 + b) * K_ + (tx << 2)) = o;
  }
}

// per-row scores(tanh)+softmax -> att probs (f32) in scores[row*256+l]
__global__ __launch_bounds__(256) void k_score(const float* __restrict__ xt,
    const float* __restrict__ yt, const float* __restrict__ v,
    const int* __restrict__ act, const unsigned char* __restrict__ xmask,
    float* __restrict__ scores) {
  __shared__ float yts[K_], vas[K_];
  __shared__ float sc[256], buf[256];
  int tid = threadIdx.x;
  int row = blockIdx.x;          // s*16+b
  int b = row & 15;
  if (tid < K_) {
    yts[tid] = yt[row * K_ + tid];
    vas[tid] = v[act[b] * K_ + tid];
  }
  __syncthreads();
  {
    const float4* xr = (const float4*)(xt + (b * 256 + tid) * K_);
    const float4* yr = (const float4*)yts;
    const float4* vr = (const float4*)vas;
    float acc = 0.f;
#pragma unroll
    for (int q = 0; q < 16; ++q) {
      float4 xv = xr[q], yv = yr[q], vv = vr[q];
      acc += vv.x * fast_tanh(xv.x + yv.x);
      acc += vv.y * fast_tanh(xv.y + yv.y);
      acc += vv.z * fast_tanh(xv.z + yv.z);
      acc += vv.w * fast_tanh(xv.w + yv.w);
    }
    if (xmask[b * S_ + tid]) acc = -1e30f;
    sc[tid] = acc;
    buf[tid] = acc;
  }
  __syncthreads();
  for (int st = 128; st; st >>= 1) {
    if (tid < st) buf[tid] = fmaxf(buf[tid], buf[tid + st]);
    __syncthreads();
  }
  float m = buf[0];
  __syncthreads();
  float p = __expf(sc[tid] - m);
  buf[tid] = p;
  __syncthreads();
  for (int st = 128; st; st >>= 1) {
    if (tid < st) buf[tid] += buf[tid + st];
    __syncthreads();
  }
  scores[row * 256 + tid] = p / buf[0];
}

// tiled f32: pools = att @ x[b] ; writes inputs_bf = [bf16(cur) | bf16(pools)]
__global__ __launch_bounds__(256) void k_pool(const float* __restrict__ scores,
    const float* __restrict__ x, const float* __restrict__ curb,
    int sstride, int bstride, u16* __restrict__ inp) {
  __shared__ float As[16][65], Bs[16][68];
  int b = blockIdx.z;
  int s0 = blockIdx.x * 64, d0 = blockIdx.y * 64;
  const float* X = x + b * (S_ * D_);
  int tid = threadIdx.x;
  int tx = tid & 15, ty = tid >> 4;
  int am = tid >> 2, ak = (tid & 3) << 2;
  float acc[4][4] = {};
  for (int kk = 0; kk < 256; kk += 16) {
    float4 av = *(const float4*)(scores + ((s0 + am) * 16 + b) * 256 + kk + ak);
    As[ak + 0][am] = av.x; As[ak + 1][am] = av.y;
    As[ak + 2][am] = av.z; As[ak + 3][am] = av.w;
    float4 bv = *(const float4*)(X + (kk + ty) * D_ + d0 + (tx << 2));
    *(float4*)&Bs[ty][tx << 2] = bv;
    __syncthreads();
#pragma unroll
    for (int k = 0; k < 16; ++k) {
      float a0 = As[k][(ty << 2) + 0], a1 = As[k][(ty << 2) + 1];
      float a2 = As[k][(ty << 2) + 2], a3 = As[k][(ty << 2) + 3];
      float b0 = Bs[k][(tx << 2) + 0], b1v = Bs[k][(tx << 2) + 1];
      float b2v = Bs[k][(tx << 2) + 2], b3v = Bs[k][(tx << 2) + 3];
      acc[0][0] += a0 * b0; acc[0][1] += a0 * b1v; acc[0][2] += a0 * b2v; acc[0][3] += a0 * b3v;
      acc[1][0] += a1 * b0; acc[1][1] += a1 * b1v; acc[1][2] += a1 * b2v; acc[1][3] += a1 * b3v;
      acc[2][0] += a2 * b0; acc[2][1] += a2 * b1v; acc[2][2] += a2 * b2v; acc[2][3] += a2 * b3v;
      acc[3][0] += a3 * b0; acc[3][1] += a3 * b1v; acc[3][2] += a3 * b2v; acc[3][3] += a3 * b3v;
    }
    __syncthreads();
  }
#pragma unroll
  for (int i = 0; i < 4; ++i) {
    int row = (s0 + (ty << 2) + i) * 16 + b;
    ushort4 o;
    o.x = f2bf(acc[i][0]); o.y = f2bf(acc[i][1]);
    o.z = f2bf(acc[i][2]); o.w = f2bf(acc[i][3]);
    *(ushort4*)(inp + row * SIN + 256 + d0 + (tx << 2)) = o;
  }
  // cur-copy for the same 64x64 region
  int r = tid >> 2, cbase = (tid & 3) << 4;
#pragma unroll
  for (int j = 0; j < 4; ++j) {
    float4 v4 = *(const float4*)(curb + b * bstride + (s0 + r) * sstride + d0 + cbase + j * 4);
    ushort4 o;
    o.x = f2bf(v4.x); o.y = f2bf(v4.y); o.z = f2bf(v4.z); o.w = f2bf(v4.w);
    *(ushort4*)(inp + ((s0 + r) * 16 + b) * SIN + d0 + cbase + j * 4) = o;
  }
}

// bf16 MFMA GEMM: U(dir) = inp(4096x512) @ W(dir)(512x512); 128x128 tile, BK=64
__global__ __launch_bounds__(256) void k_mfma(const u16* __restrict__ inp,
    const u16* __restrict__ wt, float* __restrict__ Uf, float* __restrict__ Ub,
    int layer) {
  __shared__ u16 As[128][72];
  __shared__ u16 Bs[128][72];
  float* U = blockIdx.z ? Ub : Uf;
  const u16* W = wt + (layer * 2 + blockIdx.z) * 262144;   // [n][k]
  int m0 = blockIdx.x * 128, n0 = blockIdx.y * 128;
  int tid = threadIdx.x;
  int wid = tid >> 6, lane = tid & 63;
  int wm = wid >> 1, wn = wid & 1;
  f32x4 acc[4][4];
#pragma unroll
  for (int i = 0; i < 4; ++i)
#pragma unroll
    for (int j = 0; j < 4; ++j) acc[i][j] = (f32x4){0.f, 0.f, 0.f, 0.f};
  int srow = tid >> 1, shalf = tid & 1;
  int lrow = lane & 15, lk = (lane >> 4) << 3;
  for (int kk = 0; kk < 512; kk += 64) {
    const u16* ga = inp + (m0 + srow) * SIN + kk + shalf * 32;
    const u16* gb = W + (n0 + srow) * 512 + kk + shalf * 32;
#pragma unroll
    for (int j = 0; j < 4; ++j) {
      *(short8*)&As[srow][shalf * 32 + j * 8] = *(const short8*)(ga + j * 8);
      *(short8*)&Bs[srow][shalf * 32 + j * 8] = *(const short8*)(gb + j * 8);
    }
    __syncthreads();
#pragma unroll
    for (int ks = 0; ks < 2; ++ks) {
      short8 af[4], bf[4];
#pragma unroll
      for (int mi = 0; mi < 4; ++mi)
        af[mi] = *(const short8*)&As[wm * 64 + mi * 16 + lrow][ks * 32 + lk];
#pragma unroll
      for (int ni = 0; ni < 4; ++ni)
        bf[ni] = *(const short8*)&Bs[wn * 64 + ni * 16 + lrow][ks * 32 + lk];
#pragma unroll
      for (int mi = 0; mi < 4; ++mi)
#pragma unroll
        for (int ni = 0; ni < 4; ++ni)
          acc[mi][ni] = __builtin_amdgcn_mfma_f32_16x16x32_bf16(
              af[mi], bf[ni], acc[mi][ni], 0, 0, 0);
    }
    __syncthreads();
  }
#pragma unroll
  for (int mi = 0; mi < 4; ++mi)
#pragma unroll
    for (int ni = 0; ni < 4; ++ni) {
      int r0 = m0 + wm * 64 + mi * 16 + ((lane >> 4) << 2);
      int c = n0 + wn * 64 + ni * 16 + (lane & 15);
#pragma unroll
      for (int r = 0; r < 4; ++r)
        U[(r0 + r) * F4H + c] = acc[mi][ni][r];
    }
}

// SRU recurrence; both dirs forward (matches reference); prefetched
__global__ __launch_bounds__(64) void k_scan(const float* __restrict__ Uf,
    const float* __restrict__ Ub, const float* __restrict__ bfp,
    const float* __restrict__ bbp, float* __restrict__ next) {
  int gid = blockIdx.x * 64 + threadIdx.x;   // 4096
  int dir = gid >> 11;
  int rem = gid & 2047;
  int b = rem >> 7;
  int h = rem & 127;
  const float* U = dir ? Ub : Uf;
  const float* bias = dir ? bbp : bfp;
  float bfv = bias[h];
  float brv = bias[128 + h];
  float c = 0.f;
  float* op = next + b * 256 + dir * 128 + h;
  const float* up = U + b * 512 + h;
  float u0 = up[0], uf = up[128], ur = up[256], hw = up[384];
  for (int s = 0; s < 256; ++s) {
    float n0 = 0.f, nf = 0.f, nr = 0.f, nh = 0.f;
    if (s < 255) {
      const float* q = up + (s + 1) * 8192;
      n0 = q[0]; nf = q[128]; nr = q[256]; nh = q[384];
    }
    float f = fast_sigmoid(uf + bfv);
    float r = fast_sigmoid(ur + brv);
    c = f * (c - u0) + u0;
    float hv = r * fast_tanh(c) + (1.f - r) * hw;
    op[s * 4096] = hv;
    u0 = n0; uf = nf; ur = nr; hw = nh;
  }
}

// out[b][s][d] = cur[(s*16+b)*256+d]; status==0 -> sentinel 20.0
__global__ __launch_bounds__(256) void k_out(const float* __restrict__ cur,
    const int* __restrict__ status, float* __restrict__ out) {
  int idx = blockIdx.x * 256 + threadIdx.x;
  int d = idx & 255;
  int s = (idx >> 8) & 255;
  int b = idx >> 16;
  out[idx] = (*status) ? cur[(((s << 4) + b) << 8) + d] : 20.0f;
}

__global__ __launch_bounds__(256) void k_fill(float* out, float v, int n) {
  int idx = blockIdx.x * 256 + threadIdx.x;
  if (idx < n) out[idx] = v;
}

extern "C" void kernel_launch(void* const* d_in, const int* in_sizes, int n_in,
                              void* d_out, int out_size, void* d_ws, size_t ws_size,
                              hipStream_t stream) {
  float* out = (float*)d_out;
  int fill_grid = (out_size + 255) / 256;

  const int exp_sizes[12] = {1048576, 4096, 16, 131072, 512, 131072, 512, 512,
                             524288, 512, 524288, 512};
  bool env_ok = (n_in == 12);
  if (env_ok)
    for (int i = 0; i < 12; ++i) env_ok = env_ok && (in_sizes[i] == exp_sizes[i]);
  if (!env_ok) {
    k_fill<<<fill_grid, 256, 0, stream>>>(out, 10.0f, out_size);
    return;
  }

  const float* x    = (const float*)d_in[0];
  const unsigned char* xmask = (const unsigned char*)d_in[1];
  const float* w1   = (const float*)d_in[3];
  const float* b1   = (const float*)d_in[4];
  const float* w2   = (const float*)d_in[5];
  const float* b2   = (const float*)d_in[6];
  const float* v    = (const float*)d_in[7];
  const float* sw_f = (const float*)d_in[8];
  const float* sb_f = (const float*)d_in[9];
  const float* sw_b = (const float*)d_in[10];
  const float* sb_b = (const float*)d_in[11];

  float* ws = (float*)d_ws;
  size_t off = 0;
  float* pb0    = ws + off; off += 1048576;
  float* pb1    = ws + off; off += 1048576;
  float* xt     = ws + off; off += 262144;
  float* yt     = ws + off; off += 262144;
  float* scores = ws + off; off += 1048576;
  float* Uf     = ws + off; off += 2097152;
  float* Ub     = ws + off; off += 2097152;
  u16*   inp    = (u16*)(ws + off); off += 1048576;   // 2M u16
  u16*   wt     = (u16*)(ws + off); off += 524288;    // 1M u16
  int*   act    = (int*)(ws + off); off += 16;
  int*   status = (int*)(ws + off); off += 16;

  if (ws_size < off * sizeof(float)) {
    k_fill<<<fill_grid, 256, 0, stream>>>(out, 30.0f, out_size);
    return;
  }

  k_act<<<1, 64, 0, stream>>>((const int*)d_in[2], act, status);
  k_prep<<<4096, 256, 0, stream>>>(sw_f, sw_b, wt);
  k_xt<<<dim3(4, 16), 256, 0, stream>>>(x, act, w1, b1, xt);

  for (int layer = 0; layer < 2; ++layer) {
    const float* curb = layer ? pb0 : x;
    int sstride = layer ? 4096 : 256;
    int bstride = layer ? 256 : 65536;
    float* nxt = layer ? pb1 : pb0;
    k_yt<<<dim3(4, 16), 256, 0, stream>>>(curb, sstride, bstride, act, w2, b2, yt);
    k_score<<<4096, 256, 0, stream>>>(xt, yt, v, act, xmask, scores);
    k_pool<<<dim3(4, 4, 16), 256, 0, stream>>>(scores, x, curb, sstride, bstride, inp);
    k_mfma<<<dim3(32, 4, 2), 256, 0, stream>>>(inp, wt, Uf, Ub, layer);
    k_scan<<<64, 64, 0, stream>>>(Uf, Ub, sb_f + layer * 256, sb_b + layer * 256, nxt);
  }
  k_out<<<4096, 256, 0, stream>>>(pb1, status, out);
}

// Round 8
// 277.421 us; speedup vs baseline: 4.9601x; 1.1886x over previous
//
#include <hip/hip_runtime.h>
#include <hip/hip_bf16.h>

#define S_ 256
#define D_ 256
#define K_ 64
#define SIN 512
#define F4H 512

typedef unsigned short u16;
typedef __attribute__((ext_vector_type(8))) short short8;
typedef __attribute__((ext_vector_type(4))) float f32x4;

__device__ __forceinline__ float fast_sigmoid(float x) {
  return 1.0f / (1.0f + __expf(-x));
}
__device__ __forceinline__ float fast_tanh(float x) {
  return 1.0f - 2.0f / (__expf(2.0f * x) + 1.0f);
}
__device__ __forceinline__ u16 f2bf(float f) {   // RNE f32->bf16
  unsigned int u = __float_as_uint(f);
  return (u16)((u + 0x7fff + ((u >> 16) & 1)) >> 16);
}

// actions decode: int32 vs int64 autodetect; status=1 iff all in [0,8)
__global__ void k_act(const int* __restrict__ a, int* __restrict__ act_out,
                      int* __restrict__ status) {
  if (threadIdx.x == 0 && blockIdx.x == 0) {
    bool oddzero = true;
    for (int i = 1; i < 16; i += 2) oddzero = oddzero && (a[i] == 0);
    bool ok = true;
    for (int b = 0; b < 16; ++b) {
      int v = oddzero ? a[2 * b] : a[b];
      act_out[b] = (v < 0) ? 0 : (v > 7 ? 7 : v);
      ok = ok && (v >= 0 && v < 8);
    }
    *status = ok ? 1 : 0;
  }
}

// SRU weights f32 -> bf16, transposed to [layer*2+dir][n][k] (k contiguous)
__global__ __launch_bounds__(256) void k_prep(const float* __restrict__ sw_f,
    const float* __restrict__ sw_b, u16* __restrict__ wt) {
  int idx = blockIdx.x * 256 + threadIdx.x;   // 4*512*512
  int m = idx >> 18;
  int rem = idx & 262143;
  int n = rem >> 9, kd = rem & 511;
  int layer = m >> 1;
  const float* src = (m & 1) ? sw_b : sw_f;
  wt[idx] = f2bf(src[layer * 262144 + kd * 512 + n]);
}

// tiled: xt[(b*256+l)*64+n] = b1[a][n] + sum_d x[b][l][d]*w1[a][d][n]
__global__ __launch_bounds__(256) void k_xt(const float* __restrict__ x,
    const int* __restrict__ act, const float* __restrict__ w1,
    const float* __restrict__ b1, float* __restrict__ xt) {
  __shared__ float As[16][65], Bs[16][68];
  int b = blockIdx.y;
  int a = act[b];
  int l0 = blockIdx.x * 64;
  const float* A = x + b * (S_ * D_);
  const float* W = w1 + a * (D_ * K_);
  int tid = threadIdx.x;
  int tx = tid & 15, ty = tid >> 4;
  int am = tid >> 2, ak = (tid & 3) << 2;
  float acc[4][4] = {};
  for (int kk = 0; kk < D_; kk += 16) {
    float4 av = *(const float4*)(A + (l0 + am) * D_ + kk + ak);
    As[ak + 0][am] = av.x; As[ak + 1][am] = av.y;
    As[ak + 2][am] = av.z; As[ak + 3][am] = av.w;
    float4 bv = *(const float4*)(W + (kk + ty) * K_ + (tx << 2));
    *(float4*)&Bs[ty][tx << 2] = bv;
    __syncthreads();
#pragma unroll
    for (int k = 0; k < 16; ++k) {
      float a0 = As[k][(ty << 2) + 0], a1 = As[k][(ty << 2) + 1];
      float a2 = As[k][(ty << 2) + 2], a3 = As[k][(ty << 2) + 3];
      float b0 = Bs[k][(tx << 2) + 0], b1v = Bs[k][(tx << 2) + 1];
      float b2v = Bs[k][(tx << 2) + 2], b3v = Bs[k][(tx << 2) + 3];
      acc[0][0] += a0 * b0; acc[0][1] += a0 * b1v; acc[0][2] += a0 * b2v; acc[0][3] += a0 * b3v;
      acc[1][0] += a1 * b0; acc[1][1] += a1 * b1v; acc[1][2] += a1 * b2v; acc[1][3] += a1 * b3v;
      acc[2][0] += a2 * b0; acc[2][1] += a2 * b1v; acc[2][2] += a2 * b2v; acc[2][3] += a2 * b3v;
      acc[3][0] += a3 * b0; acc[3][1] += a3 * b1v; acc[3][2] += a3 * b2v; acc[3][3] += a3 * b3v;
    }
    __syncthreads();
  }
  float4 bias = *(const float4*)(b1 + a * K_ + (tx << 2));
#pragma unroll
  for (int i = 0; i < 4; ++i) {
    float4 o = make_float4(acc[i][0] + bias.x, acc[i][1] + bias.y,
                           acc[i][2] + bias.z, acc[i][3] + bias.w);
    *(float4*)(xt + (b * 256 + l0 + (ty << 2) + i) * K_ + (tx << 2)) = o;
  }
}

// tiled: yt[((s0+m)*16+b)*64+n] = b2[a][n] + sum_d cur[s][d]*w2[a][d][n]
__global__ __launch_bounds__(256) void k_yt(const float* __restrict__ curb,
    int sstride, int bstride, const int* __restrict__ act,
    const float* __restrict__ w2, const float* __restrict__ b2,
    float* __restrict__ yt) {
  __shared__ float As[16][65], Bs[16][68];
  int b = blockIdx.y;
  int a = act[b];
  int s0 = blockIdx.x * 64;
  const float* A = curb + b * bstride;
  const float* W = w2 + a * (D_ * K_);
  int tid = threadIdx.x;
  int tx = tid & 15, ty = tid >> 4;
  int am = tid >> 2, ak = (tid & 3) << 2;
  float acc[4][4] = {};
  for (int kk = 0; kk < D_; kk += 16) {
    float4 av = *(const float4*)(A + (s0 + am) * sstride + kk + ak);
    As[ak + 0][am] = av.x; As[ak + 1][am] = av.y;
    As[ak + 2][am] = av.z; As[ak + 3][am] = av.w;
    float4 bv = *(const float4*)(W + (kk + ty) * K_ + (tx << 2));
    *(float4*)&Bs[ty][tx << 2] = bv;
    __syncthreads();
#pragma unroll
    for (int k = 0; k < 16; ++k) {
      float a0 = As[k][(ty << 2) + 0], a1 = As[k][(ty << 2) + 1];
      float a2 = As[k][(ty << 2) + 2], a3 = As[k][(ty << 2) + 3];
      float b0 = Bs[k][(tx << 2) + 0], b1v = Bs[k][(tx << 2) + 1];
      float b2v = Bs[k][(tx << 2) + 2], b3v = Bs[k][(tx << 2) + 3];
      acc[0][0] += a0 * b0; acc[0][1] += a0 * b1v; acc[0][2] += a0 * b2v; acc[0][3] += a0 * b3v;
      acc[1][0] += a1 * b0; acc[1][1] += a1 * b1v; acc[1][2] += a1 * b2v; acc[1][3] += a1 * b3v;
      acc[2][0] += a2 * b0; acc[2][1] += a2 * b1v; acc[2][2] += a2 * b2v; acc[2][3] += a2 * b3v;
      acc[3][0] += a3 * b0; acc[3][1] += a3 * b1v; acc[3][2] += a3 * b2v; acc[3][3] += a3 * b3v;
    }
    __syncthreads();
  }
  float4 bias = *(const float4*)(b2 + a * K_ + (tx << 2));
#pragma unroll
  for (int i = 0; i < 4; ++i) {
    float4 o = make_float4(acc[i][0] + bias.x, acc[i][1] + bias.y,
                           acc[i][2] + bias.z, acc[i][3] + bias.w);
    *(float4*)(yt + ((s0 + (ty << 2) + i) * 16 + b) * K_ + (tx << 2)) = o;
  }
}

// per-row scores(tanh)+softmax -> att probs (f32) in scores[row*256+l]
__global__ __launch_bounds__(256) void k_score(const float* __restrict__ xt,
    const float* __restrict__ yt, const float* __restrict__ v,
    const int* __restrict__ act, const unsigned char* __restrict__ xmask,
    float* __restrict__ scores) {
  __shared__ float yts[K_], vas[K_];
  __shared__ float sc[256], buf[256];
  int tid = threadIdx.x;
  int row = blockIdx.x;          // s*16+b
  int b = row & 15;
  if (tid < K_) {
    yts[tid] = yt[row * K_ + tid];
    vas[tid] = v[act[b] * K_ + tid];
  }
  __syncthreads();
  {
    const float4* xr = (const float4*)(xt + (b * 256 + tid) * K_);
    const float4* yr = (const float4*)yts;
    const float4* vr = (const float4*)vas;
    float acc = 0.f;
#pragma unroll
    for (int q = 0; q < 16; ++q) {
      float4 xv = xr[q], yv = yr[q], vv = vr[q];
      acc += vv.x * fast_tanh(xv.x + yv.x);
      acc += vv.y * fast_tanh(xv.y + yv.y);
      acc += vv.z * fast_tanh(xv.z + yv.z);
      acc += vv.w * fast_tanh(xv.w + yv.w);
    }
    if (xmask[b * S_ + tid]) acc = -1e30f;
    sc[tid] = acc;
    buf[tid] = acc;
  }
  __syncthreads();
  for (int st = 128; st; st >>= 1) {
    if (tid < st) buf[tid] = fmaxf(buf[tid], buf[tid + st]);
    __syncthreads();
  }
  float m = buf[0];
  __syncthreads();
  float p = __expf(sc[tid] - m);
  buf[tid] = p;
  __syncthreads();
  for (int st = 128; st; st >>= 1) {
    if (tid < st) buf[tid] += buf[tid + st];
    __syncthreads();
  }
  scores[row * 256 + tid] = p / buf[0];
}

// tiled f32: pools = att @ x[b] ; writes inputs_bf = [bf16(cur) | bf16(pools)]
__global__ __launch_bounds__(256) void k_pool(const float* __restrict__ scores,
    const float* __restrict__ x, const float* __restrict__ curb,
    int sstride, int bstride, u16* __restrict__ inp) {
  __shared__ float As[16][65], Bs[16][68];
  int b = blockIdx.z;
  int s0 = blockIdx.x * 64, d0 = blockIdx.y * 64;
  const float* X = x + b * (S_ * D_);
  int tid = threadIdx.x;
  int tx = tid & 15, ty = tid >> 4;
  int am = tid >> 2, ak = (tid & 3) << 2;
  float acc[4][4] = {};
  for (int kk = 0; kk < 256; kk += 16) {
    float4 av = *(const float4*)(scores + ((s0 + am) * 16 + b) * 256 + kk + ak);
    As[ak + 0][am] = av.x; As[ak + 1][am] = av.y;
    As[ak + 2][am] = av.z; As[ak + 3][am] = av.w;
    float4 bv = *(const float4*)(X + (kk + ty) * D_ + d0 + (tx << 2));
    *(float4*)&Bs[ty][tx << 2] = bv;
    __syncthreads();
#pragma unroll
    for (int k = 0; k < 16; ++k) {
      float a0 = As[k][(ty << 2) + 0], a1 = As[k][(ty << 2) + 1];
      float a2 = As[k][(ty << 2) + 2], a3 = As[k][(ty << 2) + 3];
      float b0 = Bs[k][(tx << 2) + 0], b1v = Bs[k][(tx << 2) + 1];
      float b2v = Bs[k][(tx << 2) + 2], b3v = Bs[k][(tx << 2) + 3];
      acc[0][0] += a0 * b0; acc[0][1] += a0 * b1v; acc[0][2] += a0 * b2v; acc[0][3] += a0 * b3v;
      acc[1][0] += a1 * b0; acc[1][1] += a1 * b1v; acc[1][2] += a1 * b2v; acc[1][3] += a1 * b3v;
      acc[2][0] += a2 * b0; acc[2][1] += a2 * b1v; acc[2][2] += a2 * b2v; acc[2][3] += a2 * b3v;
      acc[3][0] += a3 * b0; acc[3][1] += a3 * b1v; acc[3][2] += a3 * b2v; acc[3][3] += a3 * b3v;
    }
    __syncthreads();
  }
#pragma unroll
  for (int i = 0; i < 4; ++i) {
    int row = (s0 + (ty << 2) + i) * 16 + b;
    ushort4 o;
    o.x = f2bf(acc[i][0]); o.y = f2bf(acc[i][1]);
    o.z = f2bf(acc[i][2]); o.w = f2bf(acc[i][3]);
    *(ushort4*)(inp + row * SIN + 256 + d0 + (tx << 2)) = o;
  }
  int r = tid >> 2, cbase = (tid & 3) << 4;
#pragma unroll
  for (int j = 0; j < 4; ++j) {
    float4 v4 = *(const float4*)(curb + b * bstride + (s0 + r) * sstride + d0 + cbase + j * 4);
    ushort4 o;
    o.x = f2bf(v4.x); o.y = f2bf(v4.y); o.z = f2bf(v4.z); o.w = f2bf(v4.w);
    *(ushort4*)(inp + ((s0 + r) * 16 + b) * SIN + d0 + cbase + j * 4) = o;
  }
}

// bf16 MFMA GEMM: U(dir) = inp(4096x512) @ W(dir)(512x512); 128x128 tile, BK=64
__global__ __launch_bounds__(256) void k_mfma(const u16* __restrict__ inp,
    const u16* __restrict__ wt, float* __restrict__ Uf, float* __restrict__ Ub,
    int layer) {
  __shared__ u16 As[128][72];
  __shared__ u16 Bs[128][72];
  float* U = blockIdx.z ? Ub : Uf;
  const u16* W = wt + (layer * 2 + blockIdx.z) * 262144;   // [n][k]
  int m0 = blockIdx.x * 128, n0 = blockIdx.y * 128;
  int tid = threadIdx.x;
  int wid = tid >> 6, lane = tid & 63;
  int wm = wid >> 1, wn = wid & 1;
  f32x4 acc[4][4];
#pragma unroll
  for (int i = 0; i < 4; ++i)
#pragma unroll
    for (int j = 0; j < 4; ++j) acc[i][j] = (f32x4){0.f, 0.f, 0.f, 0.f};
  int srow = tid >> 1, shalf = tid & 1;
  int lrow = lane & 15, lk = (lane >> 4) << 3;
  for (int kk = 0; kk < 512; kk += 64) {
    const u16* ga = inp + (m0 + srow) * SIN + kk + shalf * 32;
    const u16* gb = W + (n0 + srow) * 512 + kk + shalf * 32;
#pragma unroll
    for (int j = 0; j < 4; ++j) {
      *(short8*)&As[srow][shalf * 32 + j * 8] = *(const short8*)(ga + j * 8);
      *(short8*)&Bs[srow][shalf * 32 + j * 8] = *(const short8*)(gb + j * 8);
    }
    __syncthreads();
#pragma unroll
    for (int ks = 0; ks < 2; ++ks) {
      short8 af[4], bf[4];
#pragma unroll
      for (int mi = 0; mi < 4; ++mi)
        af[mi] = *(const short8*)&As[wm * 64 + mi * 16 + lrow][ks * 32 + lk];
#pragma unroll
      for (int ni = 0; ni < 4; ++ni)
        bf[ni] = *(const short8*)&Bs[wn * 64 + ni * 16 + lrow][ks * 32 + lk];
#pragma unroll
      for (int mi = 0; mi < 4; ++mi)
#pragma unroll
        for (int ni = 0; ni < 4; ++ni)
          acc[mi][ni] = __builtin_amdgcn_mfma_f32_16x16x32_bf16(
              af[mi], bf[ni], acc[mi][ni], 0, 0, 0);
    }
    __syncthreads();
  }
#pragma unroll
  for (int mi = 0; mi < 4; ++mi)
#pragma unroll
    for (int ni = 0; ni < 4; ++ni) {
      int r0 = m0 + wm * 64 + mi * 16 + ((lane >> 4) << 2);
      int c = n0 + wn * 64 + ni * 16 + (lane & 15);
#pragma unroll
      for (int r = 0; r < 4; ++r)
        U[(r0 + r) * F4H + c] = acc[mi][ni][r];
    }
}

// SRU recurrence; deep register prefetch (2 banks x 8 steps, 32 loads in flight)
#define LD(P, s) { const float* q = up + (s) * 8192; \
  P##0[(s) & 7] = q[0]; P##f[(s) & 7] = q[128]; \
  P##r[(s) & 7] = q[256]; P##h[(s) & 7] = q[384]; }
#define STEP(P, s) { \
  float f = fast_sigmoid(P##f[(s) & 7] + bfv); \
  float r = fast_sigmoid(P##r[(s) & 7] + brv); \
  c = f * (c - P##0[(s) & 7]) + P##0[(s) & 7]; \
  op[(s) * 4096] = r * fast_tanh(c) + (1.f - r) * P##h[(s) & 7]; }
__global__ __launch_bounds__(64) void k_scan(const float* __restrict__ Uf,
    const float* __restrict__ Ub, const float* __restrict__ bfp,
    const float* __restrict__ bbp, float* __restrict__ next) {
  int gid = blockIdx.x * 64 + threadIdx.x;   // 4096
  int dir = gid >> 11;
  int rem = gid & 2047;
  int b = rem >> 7;
  int h = rem & 127;
  const float* U = dir ? Ub : Uf;
  const float* bias = dir ? bbp : bfp;
  float bfv = bias[h];
  float brv = bias[128 + h];
  float c = 0.f;
  float* op = next + b * 256 + dir * 128 + h;
  const float* up = U + b * 512 + h;
  float A0[8], Af[8], Ar[8], Ah[8];
  float B0[8], Bf[8], Br[8], Bh[8];
#pragma unroll
  for (int j = 0; j < 8; ++j) LD(A, j)
  for (int chunk = 0; chunk < 256; chunk += 16) {
#pragma unroll
    for (int j = 0; j < 8; ++j) LD(B, chunk + 8 + j)       // issue bank B
#pragma unroll
    for (int j = 0; j < 8; ++j) STEP(A, chunk + j)         // compute bank A
    if (chunk + 16 < 256) {
#pragma unroll
      for (int j = 0; j < 8; ++j) LD(A, chunk + 16 + j)    // issue bank A
    }
#pragma unroll
    for (int j = 0; j < 8; ++j) STEP(B, chunk + 8 + j)     // compute bank B
  }
}

// out[b][s][d] = cur[(s*16+b)*256+d]; status==0 -> sentinel 20.0
__global__ __launch_bounds__(256) void k_out(const float* __restrict__ cur,
    const int* __restrict__ status, float* __restrict__ out) {
  int idx = blockIdx.x * 256 + threadIdx.x;
  int d = idx & 255;
  int s = (idx >> 8) & 255;
  int b = idx >> 16;
  out[idx] = (*status) ? cur[(((s << 4) + b) << 8) + d] : 20.0f;
}

__global__ __launch_bounds__(256) void k_fill(float* out, float v, int n) {
  int idx = blockIdx.x * 256 + threadIdx.x;
  if (idx < n) out[idx] = v;
}

extern "C" void kernel_launch(void* const* d_in, const int* in_sizes, int n_in,
                              void* d_out, int out_size, void* d_ws, size_t ws_size,
                              hipStream_t stream) {
  float* out = (float*)d_out;
  int fill_grid = (out_size + 255) / 256;

  const int exp_sizes[12] = {1048576, 4096, 16, 131072, 512, 131072, 512, 512,
                             524288, 512, 524288, 512};
  bool env_ok = (n_in == 12);
  if (env_ok)
    for (int i = 0; i < 12; ++i) env_ok = env_ok && (in_sizes[i] == exp_sizes[i]);
  if (!env_ok) {
    k_fill<<<fill_grid, 256, 0, stream>>>(out, 10.0f, out_size);
    return;
  }

  const float* x    = (const float*)d_in[0];
  const unsigned char* xmask = (const unsigned char*)d_in[1];
  const float* w1   = (const float*)d_in[3];
  const float* b1   = (const float*)d_in[4];
  const float* w2   = (const float*)d_in[5];
  const float* b2   = (const float*)d_in[6];
  const float* v    = (const float*)d_in[7];
  const float* sw_f = (const float*)d_in[8];
  const float* sb_f = (const float*)d_in[9];
  const float* sw_b = (const float*)d_in[10];
  const float* sb_b = (const float*)d_in[11];

  float* ws = (float*)d_ws;
  size_t off = 0;
  float* pb0    = ws + off; off += 1048576;
  float* pb1    = ws + off; off += 1048576;
  float* xt     = ws + off; off += 262144;
  float* yt     = ws + off; off += 262144;
  float* scores = ws + off; off += 1048576;
  float* Uf     = ws + off; off += 2097152;
  float* Ub     = ws + off; off += 2097152;
  u16*   inp    = (u16*)(ws + off); off += 1048576;   // 2M u16
  u16*   wt     = (u16*)(ws + off); off += 524288;    // 1M u16
  int*   act    = (int*)(ws + off); off += 16;
  int*   status = (int*)(ws + off); off += 16;

  if (ws_size < off * sizeof(float)) {
    k_fill<<<fill_grid, 256, 0, stream>>>(out, 30.0f, out_size);
    return;
  }

  k_act<<<1, 64, 0, stream>>>((const int*)d_in[2], act, status);
  k_prep<<<4096, 256, 0, stream>>>(sw_f, sw_b, wt);
  k_xt<<<dim3(4, 16), 256, 0, stream>>>(x, act, w1, b1, xt);

  for (int layer = 0; layer < 2; ++layer) {
    const float* curb = layer ? pb0 : x;
    int sstride = layer ? 4096 : 256;
    int bstride = layer ? 256 : 65536;
    float* nxt = layer ? pb1 : pb0;
    k_yt<<<dim3(4, 16), 256, 0, stream>>>(curb, sstride, bstride, act, w2, b2, yt);
    k_score<<<4096, 256, 0, stream>>>(xt, yt, v, act, xmask, scores);
    k_pool<<<dim3(4, 4, 16), 256, 0, stream>>>(scores, x, curb, sstride, bstride, inp);
    k_mfma<<<dim3(32, 4, 2), 256, 0, stream>>>(inp, wt, Uf, Ub, layer);
    k_scan<<<64, 64, 0, stream>>>(Uf, Ub, sb_f + layer * 256, sb_b + layer * 256, nxt);
  }
  k_out<<<4096, 256, 0, stream>>>(pb1, status, out);
}

// Round 9
// 241.819 us; speedup vs baseline: 5.6903x; 1.1472x over previous
//
#include <hip/hip_runtime.h>
#include <hip/hip_bf16.h>

#define S_ 256
#define D_ 256
#define K_ 64
#define SIN 512
#define F4H 512

typedef unsigned short u16;
typedef __attribute__((ext_vector_type(8))) short short8;
typedef __attribute__((ext_vector_type(4))) float f32x4;

__device__ __forceinline__ float rcpf(float x) { return __builtin_amdgcn_rcpf(x); }
__device__ __forceinline__ float fast_sigmoid(float x) {
  return rcpf(1.0f + __expf(-x));
}
__device__ __forceinline__ float fast_tanh(float x) {
  return 1.0f - 2.0f * rcpf(__expf(2.0f * x) + 1.0f);
}
__device__ __forceinline__ u16 f2bf(float f) {   // RNE f32->bf16
  unsigned int u = __float_as_uint(f);
  return (u16)((u + 0x7fff + ((u >> 16) & 1)) >> 16);
}

// actions decode: int32 vs int64 autodetect; status=1 iff all in [0,8)
__global__ void k_act(const int* __restrict__ a, int* __restrict__ act_out,
                      int* __restrict__ status) {
  if (threadIdx.x == 0 && blockIdx.x == 0) {
    bool oddzero = true;
    for (int i = 1; i < 16; i += 2) oddzero = oddzero && (a[i] == 0);
    bool ok = true;
    for (int b = 0; b < 16; ++b) {
      int v = oddzero ? a[2 * b] : a[b];
      act_out[b] = (v < 0) ? 0 : (v > 7 ? 7 : v);
      ok = ok && (v >= 0 && v < 8);
    }
    *status = ok ? 1 : 0;
  }
}

// SRU weights f32 -> bf16, transposed to [layer*2+dir][n][k] (k contiguous)
__global__ __launch_bounds__(256) void k_prep(const float* __restrict__ sw_f,
    const float* __restrict__ sw_b, u16* __restrict__ wt) {
  int idx = blockIdx.x * 256 + threadIdx.x;   // 4*512*512
  int m = idx >> 18;
  int rem = idx & 262143;
  int n = rem >> 9, kd = rem & 511;
  int layer = m >> 1;
  const float* src = (m & 1) ? sw_b : sw_f;
  wt[idx] = f2bf(src[layer * 262144 + kd * 512 + n]);
}

// tiled: xt[(b*256+l)*64+n] = b1[a][n] + sum_d x[b][l][d]*w1[a][d][n]
__global__ __launch_bounds__(256) void k_xt(const float* __restrict__ x,
    const int* __restrict__ act, const float* __restrict__ w1,
    const float* __restrict__ b1, float* __restrict__ xt) {
  __shared__ float As[16][65], Bs[16][68];
  int b = blockIdx.y;
  int a = act[b];
  int l0 = blockIdx.x * 64;
  const float* A = x + b * (S_ * D_);
  const float* W = w1 + a * (D_ * K_);
  int tid = threadIdx.x;
  int tx = tid & 15, ty = tid >> 4;
  int am = tid >> 2, ak = (tid & 3) << 2;
  float acc[4][4] = {};
  for (int kk = 0; kk < D_; kk += 16) {
    float4 av = *(const float4*)(A + (l0 + am) * D_ + kk + ak);
    As[ak + 0][am] = av.x; As[ak + 1][am] = av.y;
    As[ak + 2][am] = av.z; As[ak + 3][am] = av.w;
    float4 bv = *(const float4*)(W + (kk + ty) * K_ + (tx << 2));
    *(float4*)&Bs[ty][tx << 2] = bv;
    __syncthreads();
#pragma unroll
    for (int k = 0; k < 16; ++k) {
      float a0 = As[k][(ty << 2) + 0], a1 = As[k][(ty << 2) + 1];
      float a2 = As[k][(ty << 2) + 2], a3 = As[k][(ty << 2) + 3];
      float b0 = Bs[k][(tx << 2) + 0], b1v = Bs[k][(tx << 2) + 1];
      float b2v = Bs[k][(tx << 2) + 2], b3v = Bs[k][(tx << 2) + 3];
      acc[0][0] += a0 * b0; acc[0][1] += a0 * b1v; acc[0][2] += a0 * b2v; acc[0][3] += a0 * b3v;
      acc[1][0] += a1 * b0; acc[1][1] += a1 * b1v; acc[1][2] += a1 * b2v; acc[1][3] += a1 * b3v;
      acc[2][0] += a2 * b0; acc[2][1] += a2 * b1v; acc[2][2] += a2 * b2v; acc[2][3] += a2 * b3v;
      acc[3][0] += a3 * b0; acc[3][1] += a3 * b1v; acc[3][2] += a3 * b2v; acc[3][3] += a3 * b3v;
    }
    __syncthreads();
  }
  float4 bias = *(const float4*)(b1 + a * K_ + (tx << 2));
#pragma unroll
  for (int i = 0; i < 4; ++i) {
    float4 o = make_float4(acc[i][0] + bias.x, acc[i][1] + bias.y,
                           acc[i][2] + bias.z, acc[i][3] + bias.w);
    *(float4*)(xt + (b * 256 + l0 + (ty << 2) + i) * K_ + (tx << 2)) = o;
  }
}

// tiled: yt[((s0+m)*16+b)*64+n] = b2[a][n] + sum_d cur[s][d]*w2[a][d][n]
__global__ __launch_bounds__(256) void k_yt(const float* __restrict__ curb,
    int sstride, int bstride, const int* __restrict__ act,
    const float* __restrict__ w2, const float* __restrict__ b2,
    float* __restrict__ yt) {
  __shared__ float As[16][65], Bs[16][68];
  int b = blockIdx.y;
  int a = act[b];
  int s0 = blockIdx.x * 64;
  const float* A = curb + b * bstride;
  const float* W = w2 + a * (D_ * K_);
  int tid = threadIdx.x;
  int tx = tid & 15, ty = tid >> 4;
  int am = tid >> 2, ak = (tid & 3) << 2;
  float acc[4][4] = {};
  for (int kk = 0; kk < D_; kk += 16) {
    float4 av = *(const float4*)(A + (s0 + am) * sstride + kk + ak);
    As[ak + 0][am] = av.x; As[ak + 1][am] = av.y;
    As[ak + 2][am] = av.z; As[ak + 3][am] = av.w;
    float4 bv = *(const float4*)(W + (kk + ty) * K_ + (tx << 2));
    *(float4*)&Bs[ty][tx << 2] = bv;
    __syncthreads();
#pragma unroll
    for (int k = 0; k < 16; ++k) {
      float a0 = As[k][(ty << 2) + 0], a1 = As[k][(ty << 2) + 1];
      float a2 = As[k][(ty << 2) + 2], a3 = As[k][(ty << 2) + 3];
      float b0 = Bs[k][(tx << 2) + 0], b1v = Bs[k][(tx << 2) + 1];
      float b2v = Bs[k][(tx << 2) + 2], b3v = Bs[k][(tx << 2) + 3];
      acc[0][0] += a0 * b0; acc[0][1] += a0 * b1v; acc[0][2] += a0 * b2v; acc[0][3] += a0 * b3v;
      acc[1][0] += a1 * b0; acc[1][1] += a1 * b1v; acc[1][2] += a1 * b2v; acc[1][3] += a1 * b3v;
      acc[2][0] += a2 * b0; acc[2][1] += a2 * b1v; acc[2][2] += a2 * b2v; acc[2][3] += a2 * b3v;
      acc[3][0] += a3 * b0; acc[3][1] += a3 * b1v; acc[3][2] += a3 * b2v; acc[3][3] += a3 * b3v;
    }
    __syncthreads();
  }
  float4 bias = *(const float4*)(b2 + a * K_ + (tx << 2));
#pragma unroll
  for (int i = 0; i < 4; ++i) {
    float4 o = make_float4(acc[i][0] + bias.x, acc[i][1] + bias.y,
                           acc[i][2] + bias.z, acc[i][3] + bias.w);
    *(float4*)(yt + ((s0 + (ty << 2) + i) * 16 + b) * K_ + (tx << 2)) = o;
  }
}

// per-row scores(tanh)+softmax -> att probs (f32) in scores[row*256+l]
__global__ __launch_bounds__(256) void k_score(const float* __restrict__ xt,
    const float* __restrict__ yt, const float* __restrict__ v,
    const int* __restrict__ act, const unsigned char* __restrict__ xmask,
    float* __restrict__ scores) {
  __shared__ float yts[K_], vas[K_];
  __shared__ float sc[256], buf[256];
  int tid = threadIdx.x;
  int row = blockIdx.x;          // s*16+b
  int b = row & 15;
  if (tid < K_) {
    yts[tid] = yt[row * K_ + tid];
    vas[tid] = v[act[b] * K_ + tid];
  }
  __syncthreads();
  {
    const float4* xr = (const float4*)(xt + (b * 256 + tid) * K_);
    const float4* yr = (const float4*)yts;
    const float4* vr = (const float4*)vas;
    float acc = 0.f;
#pragma unroll
    for (int q = 0; q < 16; ++q) {
      float4 xv = xr[q], yv = yr[q], vv = vr[q];
      acc += vv.x * fast_tanh(xv.x + yv.x);
      acc += vv.y * fast_tanh(xv.y + yv.y);
      acc += vv.z * fast_tanh(xv.z + yv.z);
      acc += vv.w * fast_tanh(xv.w + yv.w);
    }
    if (xmask[b * S_ + tid]) acc = -1e30f;
    sc[tid] = acc;
    buf[tid] = acc;
  }
  __syncthreads();
  for (int st = 128; st; st >>= 1) {
    if (tid < st) buf[tid] = fmaxf(buf[tid], buf[tid + st]);
    __syncthreads();
  }
  float m = buf[0];
  __syncthreads();
  float p = __expf(sc[tid] - m);
  buf[tid] = p;
  __syncthreads();
  for (int st = 128; st; st >>= 1) {
    if (tid < st) buf[tid] += buf[tid + st];
    __syncthreads();
  }
  scores[row * 256 + tid] = p * rcpf(buf[0]);
}

// tiled f32: pools = att @ x[b] ; writes inputs_bf = [bf16(cur) | bf16(pools)]
__global__ __launch_bounds__(256) void k_pool(const float* __restrict__ scores,
    const float* __restrict__ x, const float* __restrict__ curb,
    int sstride, int bstride, u16* __restrict__ inp) {
  __shared__ float As[16][65], Bs[16][68];
  int b = blockIdx.z;
  int s0 = blockIdx.x * 64, d0 = blockIdx.y * 64;
  const float* X = x + b * (S_ * D_);
  int tid = threadIdx.x;
  int tx = tid & 15, ty = tid >> 4;
  int am = tid >> 2, ak = (tid & 3) << 2;
  float acc[4][4] = {};
  for (int kk = 0; kk < 256; kk += 16) {
    float4 av = *(const float4*)(scores + ((s0 + am) * 16 + b) * 256 + kk + ak);
    As[ak + 0][am] = av.x; As[ak + 1][am] = av.y;
    As[ak + 2][am] = av.z; As[ak + 3][am] = av.w;
    float4 bv = *(const float4*)(X + (kk + ty) * D_ + d0 + (tx << 2));
    *(float4*)&Bs[ty][tx << 2] = bv;
    __syncthreads();
#pragma unroll
    for (int k = 0; k < 16; ++k) {
      float a0 = As[k][(ty << 2) + 0], a1 = As[k][(ty << 2) + 1];
      float a2 = As[k][(ty << 2) + 2], a3 = As[k][(ty << 2) + 3];
      float b0 = Bs[k][(tx << 2) + 0], b1v = Bs[k][(tx << 2) + 1];
      float b2v = Bs[k][(tx << 2) + 2], b3v = Bs[k][(tx << 2) + 3];
      acc[0][0] += a0 * b0; acc[0][1] += a0 * b1v; acc[0][2] += a0 * b2v; acc[0][3] += a0 * b3v;
      acc[1][0] += a1 * b0; acc[1][1] += a1 * b1v; acc[1][2] += a1 * b2v; acc[1][3] += a1 * b3v;
      acc[2][0] += a2 * b0; acc[2][1] += a2 * b1v; acc[2][2] += a2 * b2v; acc[2][3] += a2 * b3v;
      acc[3][0] += a3 * b0; acc[3][1] += a3 * b1v; acc[3][2] += a3 * b2v; acc[3][3] += a3 * b3v;
    }
    __syncthreads();
  }
#pragma unroll
  for (int i = 0; i < 4; ++i) {
    int row = (s0 + (ty << 2) + i) * 16 + b;
    ushort4 o;
    o.x = f2bf(acc[i][0]); o.y = f2bf(acc[i][1]);
    o.z = f2bf(acc[i][2]); o.w = f2bf(acc[i][3]);
    *(ushort4*)(inp + row * SIN + 256 + d0 + (tx << 2)) = o;
  }
  int r = tid >> 2, cbase = (tid & 3) << 4;
#pragma unroll
  for (int j = 0; j < 4; ++j) {
    float4 v4 = *(const float4*)(curb + b * bstride + (s0 + r) * sstride + d0 + cbase + j * 4);
    ushort4 o;
    o.x = f2bf(v4.x); o.y = f2bf(v4.y); o.z = f2bf(v4.z); o.w = f2bf(v4.w);
    *(ushort4*)(inp + ((s0 + r) * 16 + b) * SIN + d0 + cbase + j * 4) = o;
  }
}

// bf16 MFMA GEMM: U(dir) = inp(4096x512) @ W(dir)(512x512); 128x128 tile, BK=64
__global__ __launch_bounds__(256) void k_mfma(const u16* __restrict__ inp,
    const u16* __restrict__ wt, float* __restrict__ Uf, float* __restrict__ Ub,
    int layer) {
  __shared__ u16 As[128][72];
  __shared__ u16 Bs[128][72];
  float* U = blockIdx.z ? Ub : Uf;
  const u16* W = wt + (layer * 2 + blockIdx.z) * 262144;   // [n][k]
  int m0 = blockIdx.x * 128, n0 = blockIdx.y * 128;
  int tid = threadIdx.x;
  int wid = tid >> 6, lane = tid & 63;
  int wm = wid >> 1, wn = wid & 1;
  f32x4 acc[4][4];
#pragma unroll
  for (int i = 0; i < 4; ++i)
#pragma unroll
    for (int j = 0; j < 4; ++j) acc[i][j] = (f32x4){0.f, 0.f, 0.f, 0.f};
  int srow = tid >> 1, shalf = tid & 1;
  int lrow = lane & 15, lk = (lane >> 4) << 3;
  for (int kk = 0; kk < 512; kk += 64) {
    const u16* ga = inp + (m0 + srow) * SIN + kk + shalf * 32;
    const u16* gb = W + (n0 + srow) * 512 + kk + shalf * 32;
#pragma unroll
    for (int j = 0; j < 4; ++j) {
      *(short8*)&As[srow][shalf * 32 + j * 8] = *(const short8*)(ga + j * 8);
      *(short8*)&Bs[srow][shalf * 32 + j * 8] = *(const short8*)(gb + j * 8);
    }
    __syncthreads();
#pragma unroll
    for (int ks = 0; ks < 2; ++ks) {
      short8 af[4], bf[4];
#pragma unroll
      for (int mi = 0; mi < 4; ++mi)
        af[mi] = *(const short8*)&As[wm * 64 + mi * 16 + lrow][ks * 32 + lk];
#pragma unroll
      for (int ni = 0; ni < 4; ++ni)
        bf[ni] = *(const short8*)&Bs[wn * 64 + ni * 16 + lrow][ks * 32 + lk];
#pragma unroll
      for (int mi = 0; mi < 4; ++mi)
#pragma unroll
        for (int ni = 0; ni < 4; ++ni)
          acc[mi][ni] = __builtin_amdgcn_mfma_f32_16x16x32_bf16(
              af[mi], bf[ni], acc[mi][ni], 0, 0, 0);
    }
    __syncthreads();
  }
#pragma unroll
  for (int mi = 0; mi < 4; ++mi)
#pragma unroll
    for (int ni = 0; ni < 4; ++ni) {
      int r0 = m0 + wm * 64 + mi * 16 + ((lane >> 4) << 2);
      int c = n0 + wn * 64 + ni * 16 + (lane & 15);
#pragma unroll
      for (int r = 0; r < 4; ++r)
        U[(r0 + r) * F4H + c] = acc[mi][ni][r];
    }
}

// SRU recurrence; deep register prefetch (2 banks x 8 steps, 32 loads in flight)
#define LD(P, s) { const float* q = up + (s) * 8192; \
  P##0[(s) & 7] = q[0]; P##f[(s) & 7] = q[128]; \
  P##r[(s) & 7] = q[256]; P##h[(s) & 7] = q[384]; }
#define STEP(P, s) { \
  float f = fast_sigmoid(P##f[(s) & 7] + bfv); \
  float r = fast_sigmoid(P##r[(s) & 7] + brv); \
  c = f * (c - P##0[(s) & 7]) + P##0[(s) & 7]; \
  op[(s) * 4096] = r * fast_tanh(c) + (1.f - r) * P##h[(s) & 7]; }
__global__ __launch_bounds__(64) void k_scan(const float* __restrict__ Uf,
    const float* __restrict__ Ub, const float* __restrict__ bfp,
    const float* __restrict__ bbp, float* __restrict__ next) {
  int gid = blockIdx.x * 64 + threadIdx.x;   // 4096
  int dir = gid >> 11;
  int rem = gid & 2047;
  int b = rem >> 7;
  int h = rem & 127;
  const float* U = dir ? Ub : Uf;
  const float* bias = dir ? bbp : bfp;
  float bfv = bias[h];
  float brv = bias[128 + h];
  float c = 0.f;
  float* op = next + b * 256 + dir * 128 + h;
  const float* up = U + b * 512 + h;
  float A0[8], Af[8], Ar[8], Ah[8];
  float B0[8], Bf[8], Br[8], Bh[8];
#pragma unroll
  for (int j = 0; j < 8; ++j) LD(A, j)
  for (int chunk = 0; chunk < 256; chunk += 16) {
#pragma unroll
    for (int j = 0; j < 8; ++j) LD(B, chunk + 8 + j)       // issue bank B
#pragma unroll
    for (int j = 0; j < 8; ++j) STEP(A, chunk + j)         // compute bank A
    if (chunk + 16 < 256) {
#pragma unroll
      for (int j = 0; j < 8; ++j) LD(A, chunk + 16 + j)    // issue bank A
    }
#pragma unroll
    for (int j = 0; j < 8; ++j) STEP(B, chunk + 8 + j)     // compute bank B
  }
}

// out[b][s][d] = cur[(s*16+b)*256+d]; status==0 -> sentinel 20.0
__global__ __launch_bounds__(256) void k_out(const float* __restrict__ cur,
    const int* __restrict__ status, float* __restrict__ out) {
  int idx = blockIdx.x * 256 + threadIdx.x;
  int d = idx & 255;
  int s = (idx >> 8) & 255;
  int b = idx >> 16;
  out[idx] = (*status) ? cur[(((s << 4) + b) << 8) + d] : 20.0f;
}

__global__ __launch_bounds__(256) void k_fill(float* out, float v, int n) {
  int idx = blockIdx.x * 256 + threadIdx.x;
  if (idx < n) out[idx] = v;
}

extern "C" void kernel_launch(void* const* d_in, const int* in_sizes, int n_in,
                              void* d_out, int out_size, void* d_ws, size_t ws_size,
                              hipStream_t stream) {
  float* out = (float*)d_out;
  int fill_grid = (out_size + 255) / 256;

  const int exp_sizes[12] = {1048576, 4096, 16, 131072, 512, 131072, 512, 512,
                             524288, 512, 524288, 512};
  bool env_ok = (n_in == 12);
  if (env_ok)
    for (int i = 0; i < 12; ++i) env_ok = env_ok && (in_sizes[i] == exp_sizes[i]);
  if (!env_ok) {
    k_fill<<<fill_grid, 256, 0, stream>>>(out, 10.0f, out_size);
    return;
  }

  const float* x    = (const float*)d_in[0];
  const unsigned char* xmask = (const unsigned char*)d_in[1];
  const float* w1   = (const float*)d_in[3];
  const float* b1   = (const float*)d_in[4];
  const float* w2   = (const float*)d_in[5];
  const float* b2   = (const float*)d_in[6];
  const float* v    = (const float*)d_in[7];
  const float* sw_f = (const float*)d_in[8];
  const float* sb_f = (const float*)d_in[9];
  const float* sw_b = (const float*)d_in[10];
  const float* sb_b = (const float*)d_in[11];

  float* ws = (float*)d_ws;
  size_t off = 0;
  float* pb0    = ws + off; off += 1048576;
  float* pb1    = ws + off; off += 1048576;
  float* xt     = ws + off; off += 262144;
  float* yt     = ws + off; off += 262144;
  float* scores = ws + off; off += 1048576;
  float* Uf     = ws + off; off += 2097152;
  float* Ub     = ws + off; off += 2097152;
  u16*   inp    = (u16*)(ws + off); off += 1048576;   // 2M u16
  u16*   wt     = (u16*)(ws + off); off += 524288;    // 1M u16
  int*   act    = (int*)(ws + off); off += 16;
  int*   status = (int*)(ws + off); off += 16;

  if (ws_size < off * sizeof(float)) {
    k_fill<<<fill_grid, 256, 0, stream>>>(out, 30.0f, out_size);
    return;
  }

  k_act<<<1, 64, 0, stream>>>((const int*)d_in[2], act, status);
  k_prep<<<4096, 256, 0, stream>>>(sw_f, sw_b, wt);
  k_xt<<<dim3(4, 16), 256, 0, stream>>>(x, act, w1, b1, xt);

  for (int layer = 0; layer < 2; ++layer) {
    const float* curb = layer ? pb0 : x;
    int sstride = layer ? 4096 : 256;
    int bstride = layer ? 256 : 65536;
    float* nxt = layer ? pb1 : pb0;
    k_yt<<<dim3(4, 16), 256, 0, stream>>>(curb, sstride, bstride, act, w2, b2, yt);
    k_score<<<4096, 256, 0, stream>>>(xt, yt, v, act, xmask, scores);
    k_pool<<<dim3(4, 4, 16), 256, 0, stream>>>(scores, x, curb, sstride, bstride, inp);
    k_mfma<<<dim3(32, 4, 2), 256, 0, stream>>>(inp, wt, Uf, Ub, layer);
    k_scan<<<64, 64, 0, stream>>>(Uf, Ub, sb_f + layer * 256, sb_b + layer * 256, nxt);
  }
  k_out<<<4096, 256, 0, stream>>>(pb1, status, out);
}

// Round 10
// 203.437 us; speedup vs baseline: 6.7639x; 1.1887x over previous
//
#include <hip/hip_runtime.h>
#include <hip/hip_bf16.h>

#define S_ 256
#define D_ 256
#define K_ 64
#define SIN 512
#define F4H 512

typedef unsigned short u16;
typedef __attribute__((ext_vector_type(8))) short short8;
typedef __attribute__((ext_vector_type(4))) float f32x4;

__device__ __forceinline__ float rcpf(float x) { return __builtin_amdgcn_rcpf(x); }
__device__ __forceinline__ float fast_sigmoid(float x) {
  return rcpf(1.0f + __expf(-x));
}
__device__ __forceinline__ float fast_tanh(float x) {
  return 1.0f - 2.0f * rcpf(__expf(2.0f * x) + 1.0f);
}
__device__ __forceinline__ u16 f2bf(float f) {   // RNE f32->bf16
  unsigned int u = __float_as_uint(f);
  return (u16)((u + 0x7fff + ((u >> 16) & 1)) >> 16);
}

// actions decode: int32 vs int64 autodetect; status=1 iff all in [0,8)
__global__ void k_act(const int* __restrict__ a, int* __restrict__ act_out,
                      int* __restrict__ status) {
  if (threadIdx.x == 0 && blockIdx.x == 0) {
    bool oddzero = true;
    for (int i = 1; i < 16; i += 2) oddzero = oddzero && (a[i] == 0);
    bool ok = true;
    for (int b = 0; b < 16; ++b) {
      int v = oddzero ? a[2 * b] : a[b];
      act_out[b] = (v < 0) ? 0 : (v > 7 ? 7 : v);
      ok = ok && (v >= 0 && v < 8);
    }
    *status = ok ? 1 : 0;
  }
}

// SRU weights f32 -> bf16, transposed to [layer*2+dir][n][k]; LDS-tiled (both sides coalesced)
__global__ __launch_bounds__(256) void k_prep(const float* __restrict__ sw_f,
    const float* __restrict__ sw_b, u16* __restrict__ wt) {
  __shared__ u16 tile[64][66];
  int m = blockIdx.z;                 // layer*2+dir
  int layer = m >> 1;
  const float* src = (m & 1) ? sw_b : sw_f;
  int k0 = blockIdx.x * 64, n0 = blockIdx.y * 64;
  int tj = threadIdx.x & 63, ti = threadIdx.x >> 6;
#pragma unroll
  for (int i = ti; i < 64; i += 4)
    tile[i][tj] = f2bf(src[layer * 262144 + (k0 + i) * 512 + n0 + tj]);
  __syncthreads();
#pragma unroll
  for (int j = ti; j < 64; j += 4)
    wt[m * 262144 + (n0 + j) * 512 + k0 + tj] = tile[tj][j];
}

// tiled: xt[(b*256+l)*64+n] = b1[a][n] + sum_d x[b][l][d]*w1[a][d][n]
__global__ __launch_bounds__(256) void k_xt(const float* __restrict__ x,
    const int* __restrict__ act, const float* __restrict__ w1,
    const float* __restrict__ b1, float* __restrict__ xt) {
  __shared__ float As[16][65], Bs[16][68];
  int b = blockIdx.y;
  int a = act[b];
  int l0 = blockIdx.x * 64;
  const float* A = x + b * (S_ * D_);
  const float* W = w1 + a * (D_ * K_);
  int tid = threadIdx.x;
  int tx = tid & 15, ty = tid >> 4;
  int am = tid >> 2, ak = (tid & 3) << 2;
  float acc[4][4] = {};
  for (int kk = 0; kk < D_; kk += 16) {
    float4 av = *(const float4*)(A + (l0 + am) * D_ + kk + ak);
    As[ak + 0][am] = av.x; As[ak + 1][am] = av.y;
    As[ak + 2][am] = av.z; As[ak + 3][am] = av.w;
    float4 bv = *(const float4*)(W + (kk + ty) * K_ + (tx << 2));
    *(float4*)&Bs[ty][tx << 2] = bv;
    __syncthreads();
#pragma unroll
    for (int k = 0; k < 16; ++k) {
      float a0 = As[k][(ty << 2) + 0], a1 = As[k][(ty << 2) + 1];
      float a2 = As[k][(ty << 2) + 2], a3 = As[k][(ty << 2) + 3];
      float b0 = Bs[k][(tx << 2) + 0], b1v = Bs[k][(tx << 2) + 1];
      float b2v = Bs[k][(tx << 2) + 2], b3v = Bs[k][(tx << 2) + 3];
      acc[0][0] += a0 * b0; acc[0][1] += a0 * b1v; acc[0][2] += a0 * b2v; acc[0][3] += a0 * b3v;
      acc[1][0] += a1 * b0; acc[1][1] += a1 * b1v; acc[1][2] += a1 * b2v; acc[1][3] += a1 * b3v;
      acc[2][0] += a2 * b0; acc[2][1] += a2 * b1v; acc[2][2] += a2 * b2v; acc[2][3] += a2 * b3v;
      acc[3][0] += a3 * b0; acc[3][1] += a3 * b1v; acc[3][2] += a3 * b2v; acc[3][3] += a3 * b3v;
    }
    __syncthreads();
  }
  float4 bias = *(const float4*)(b1 + a * K_ + (tx << 2));
#pragma unroll
  for (int i = 0; i < 4; ++i) {
    float4 o = make_float4(acc[i][0] + bias.x, acc[i][1] + bias.y,
                           acc[i][2] + bias.z, acc[i][3] + bias.w);
    *(float4*)(xt + (b * 256 + l0 + (ty << 2) + i) * K_ + (tx << 2)) = o;
  }
}

// fused per-row: yt (in-block GEMV) + scores(tanh) + softmax -> probs in scores[row*256+l]
__global__ __launch_bounds__(256) void k_score(const float* __restrict__ xt,
    const float* __restrict__ curb, int sstride, int bstride,
    const float* __restrict__ w2, const float* __restrict__ b2,
    const float* __restrict__ v, const int* __restrict__ act,
    const unsigned char* __restrict__ xmask, float* __restrict__ scores) {
  __shared__ float yts[K_], vas[K_];
  __shared__ float curs[256];
  __shared__ float sc[256], buf[256];
  int tid = threadIdx.x;
  int row = blockIdx.x;          // s*16+b
  int b = row & 15, s = row >> 4;
  int a = act[b];
  curs[tid] = curb[b * bstride + s * sstride + tid];
  if (tid < K_) vas[tid] = v[a * K_ + tid];
  __syncthreads();
  // yt[k] = b2[a][k] + sum_d curs[d]*w2[a][d][k]  (4 threads per k)
  {
    int k = tid & 63, dseg = tid >> 6;
    const float* wcol = w2 + a * (D_ * K_) + k;
    float part = 0.f;
#pragma unroll 8
    for (int i = 0; i < 64; ++i) {
      int d = dseg * 64 + i;
      part += curs[d] * wcol[d * K_];
    }
    buf[tid] = part;
  }
  __syncthreads();
  if (tid < K_)
    yts[tid] = buf[tid] + buf[64 + tid] + buf[128 + tid] + buf[192 + tid]
             + b2[a * K_ + tid];
  __syncthreads();
  {
    const float4* xr = (const float4*)(xt + (b * 256 + tid) * K_);
    const float4* yr = (const float4*)yts;
    const float4* vr = (const float4*)vas;
    float acc = 0.f;
#pragma unroll
    for (int q = 0; q < 16; ++q) {
      float4 xv = xr[q], yv = yr[q], vv = vr[q];
      acc += vv.x * fast_tanh(xv.x + yv.x);
      acc += vv.y * fast_tanh(xv.y + yv.y);
      acc += vv.z * fast_tanh(xv.z + yv.z);
      acc += vv.w * fast_tanh(xv.w + yv.w);
    }
    if (xmask[b * S_ + tid]) acc = -1e30f;
    sc[tid] = acc;
    buf[tid] = acc;
  }
  __syncthreads();
  for (int st = 128; st; st >>= 1) {
    if (tid < st) buf[tid] = fmaxf(buf[tid], buf[tid + st]);
    __syncthreads();
  }
  float m = buf[0];
  __syncthreads();
  float p = __expf(sc[tid] - m);
  buf[tid] = p;
  __syncthreads();
  for (int st = 128; st; st >>= 1) {
    if (tid < st) buf[tid] += buf[tid + st];
    __syncthreads();
  }
  scores[row * 256 + tid] = p * rcpf(buf[0]);
}

// tiled f32: pools = att @ x[b] ; writes inputs_bf = [bf16(cur) | bf16(pools)]
__global__ __launch_bounds__(256) void k_pool(const float* __restrict__ scores,
    const float* __restrict__ x, const float* __restrict__ curb,
    int sstride, int bstride, u16* __restrict__ inp) {
  __shared__ float As[16][65], Bs[16][68];
  int b = blockIdx.z;
  int s0 = blockIdx.x * 64, d0 = blockIdx.y * 64;
  const float* X = x + b * (S_ * D_);
  int tid = threadIdx.x;
  int tx = tid & 15, ty = tid >> 4;
  int am = tid >> 2, ak = (tid & 3) << 2;
  float acc[4][4] = {};
  for (int kk = 0; kk < 256; kk += 16) {
    float4 av = *(const float4*)(scores + ((s0 + am) * 16 + b) * 256 + kk + ak);
    As[ak + 0][am] = av.x; As[ak + 1][am] = av.y;
    As[ak + 2][am] = av.z; As[ak + 3][am] = av.w;
    float4 bv = *(const float4*)(X + (kk + ty) * D_ + d0 + (tx << 2));
    *(float4*)&Bs[ty][tx << 2] = bv;
    __syncthreads();
#pragma unroll
    for (int k = 0; k < 16; ++k) {
      float a0 = As[k][(ty << 2) + 0], a1 = As[k][(ty << 2) + 1];
      float a2 = As[k][(ty << 2) + 2], a3 = As[k][(ty << 2) + 3];
      float b0 = Bs[k][(tx << 2) + 0], b1v = Bs[k][(tx << 2) + 1];
      float b2v = Bs[k][(tx << 2) + 2], b3v = Bs[k][(tx << 2) + 3];
      acc[0][0] += a0 * b0; acc[0][1] += a0 * b1v; acc[0][2] += a0 * b2v; acc[0][3] += a0 * b3v;
      acc[1][0] += a1 * b0; acc[1][1] += a1 * b1v; acc[1][2] += a1 * b2v; acc[1][3] += a1 * b3v;
      acc[2][0] += a2 * b0; acc[2][1] += a2 * b1v; acc[2][2] += a2 * b2v; acc[2][3] += a2 * b3v;
      acc[3][0] += a3 * b0; acc[3][1] += a3 * b1v; acc[3][2] += a3 * b2v; acc[3][3] += a3 * b3v;
    }
    __syncthreads();
  }
#pragma unroll
  for (int i = 0; i < 4; ++i) {
    int row = (s0 + (ty << 2) + i) * 16 + b;
    ushort4 o;
    o.x = f2bf(acc[i][0]); o.y = f2bf(acc[i][1]);
    o.z = f2bf(acc[i][2]); o.w = f2bf(acc[i][3]);
    *(ushort4*)(inp + row * SIN + 256 + d0 + (tx << 2)) = o;
  }
  int r = tid >> 2, cbase = (tid & 3) << 4;
#pragma unroll
  for (int j = 0; j < 4; ++j) {
    float4 v4 = *(const float4*)(curb + b * bstride + (s0 + r) * sstride + d0 + cbase + j * 4);
    ushort4 o;
    o.x = f2bf(v4.x); o.y = f2bf(v4.y); o.z = f2bf(v4.z); o.w = f2bf(v4.w);
    *(ushort4*)(inp + ((s0 + r) * 16 + b) * SIN + d0 + cbase + j * 4) = o;
  }
}

// bf16 MFMA GEMM: U(dir) = inp(4096x512) @ W(dir)(512x512); 128x128 tile, BK=64
__global__ __launch_bounds__(256) void k_mfma(const u16* __restrict__ inp,
    const u16* __restrict__ wt, float* __restrict__ Uf, float* __restrict__ Ub,
    int layer) {
  __shared__ u16 As[128][72];
  __shared__ u16 Bs[128][72];
  float* U = blockIdx.z ? Ub : Uf;
  const u16* W = wt + (layer * 2 + blockIdx.z) * 262144;   // [n][k]
  int m0 = blockIdx.x * 128, n0 = blockIdx.y * 128;
  int tid = threadIdx.x;
  int wid = tid >> 6, lane = tid & 63;
  int wm = wid >> 1, wn = wid & 1;
  f32x4 acc[4][4];
#pragma unroll
  for (int i = 0; i < 4; ++i)
#pragma unroll
    for (int j = 0; j < 4; ++j) acc[i][j] = (f32x4){0.f, 0.f, 0.f, 0.f};
  int srow = tid >> 1, shalf = tid & 1;
  int lrow = lane & 15, lk = (lane >> 4) << 3;
  for (int kk = 0; kk < 512; kk += 64) {
    const u16* ga = inp + (m0 + srow) * SIN + kk + shalf * 32;
    const u16* gb = W + (n0 + srow) * 512 + kk + shalf * 32;
#pragma unroll
    for (int j = 0; j < 4; ++j) {
      *(short8*)&As[srow][shalf * 32 + j * 8] = *(const short8*)(ga + j * 8);
      *(short8*)&Bs[srow][shalf * 32 + j * 8] = *(const short8*)(gb + j * 8);
    }
    __syncthreads();
#pragma unroll
    for (int ks = 0; ks < 2; ++ks) {
      short8 af[4], bf[4];
#pragma unroll
      for (int mi = 0; mi < 4; ++mi)
        af[mi] = *(const short8*)&As[wm * 64 + mi * 16 + lrow][ks * 32 + lk];
#pragma unroll
      for (int ni = 0; ni < 4; ++ni)
        bf[ni] = *(const short8*)&Bs[wn * 64 + ni * 16 + lrow][ks * 32 + lk];
#pragma unroll
      for (int mi = 0; mi < 4; ++mi)
#pragma unroll
        for (int ni = 0; ni < 4; ++ni)
          acc[mi][ni] = __builtin_amdgcn_mfma_f32_16x16x32_bf16(
              af[mi], bf[ni], acc[mi][ni], 0, 0, 0);
    }
    __syncthreads();
  }
#pragma unroll
  for (int mi = 0; mi < 4; ++mi)
#pragma unroll
    for (int ni = 0; ni < 4; ++ni) {
      int r0 = m0 + wm * 64 + mi * 16 + ((lane >> 4) << 2);
      int c = n0 + wn * 64 + ni * 16 + (lane & 15);
#pragma unroll
      for (int r = 0; r < 4; ++r)
        U[(r0 + r) * F4H + c] = acc[mi][ni][r];
    }
}

// SRU recurrence via segmented parallel scan: 16 lanes/chain, 16 steps/lane.
// c_t = f*c + (1-f)*u0 is affine; compose (A,B) per segment, shfl-scan, recompute.
__global__ __launch_bounds__(256) void k_scan(const float* __restrict__ Uf,
    const float* __restrict__ Ub, const float* __restrict__ bfp,
    const float* __restrict__ bbp, float* __restrict__ next) {
  int tid = threadIdx.x;
  int chain = blockIdx.x * 16 + (tid >> 4);   // 0..4095 = dir*2048+b*128+h
  int lane = tid & 15;
  int dir = chain >> 11;
  int rem = chain & 2047;
  int b = rem >> 7, h = rem & 127;
  const float* U = dir ? Ub : Uf;
  const float* bias = dir ? bbp : bfp;
  float bfv = bias[h], brv = bias[128 + h];
  const float* up = U + b * 512 + h;
  float* op = next + b * 256 + dir * 128 + h;
  int s0 = lane * 16;
  float fv[16], u0[16], rv[16], hw[16];
#pragma unroll
  for (int t = 0; t < 16; ++t) {
    const float* q = up + (s0 + t) * 8192;
    u0[t] = q[0]; fv[t] = q[128]; rv[t] = q[256]; hw[t] = q[384];
  }
  // local affine compose over own segment: c' = A*c + B
  float A = 1.f, Bv = 0.f;
#pragma unroll
  for (int t = 0; t < 16; ++t) {
    float f = fast_sigmoid(fv[t] + bfv);
    fv[t] = f;
    Bv = f * Bv + (1.f - f) * u0[t];
    A = A * f;
  }
  // inclusive scan across 16 lanes (earlier segment applied first)
#pragma unroll
  for (int d = 1; d < 16; d <<= 1) {
    float Ap = __shfl_up(A, d, 16);
    float Bp = __shfl_up(Bv, d, 16);
    if (lane >= d) { Bv = A * Bp + Bv; A = A * Ap; }
  }
  // exclusive: c entering this segment (c_0 = 0 -> just B of previous lane)
  float cin = __shfl_up(Bv, 1, 16);
  if (lane == 0) cin = 0.f;
  // recompute and emit
  float c = cin;
#pragma unroll
  for (int t = 0; t < 16; ++t) {
    float f = fv[t];
    c = f * (c - u0[t]) + u0[t];
    float r = fast_sigmoid(rv[t] + brv);
    op[(s0 + t) * 4096] = r * fast_tanh(c) + (1.f - r) * hw[t];
  }
}

// out[b][s][d] = cur[(s*16+b)*256+d]; status==0 -> sentinel 20.0
__global__ __launch_bounds__(256) void k_out(const float* __restrict__ cur,
    const int* __restrict__ status, float* __restrict__ out) {
  int idx = blockIdx.x * 256 + threadIdx.x;
  int d = idx & 255;
  int s = (idx >> 8) & 255;
  int b = idx >> 16;
  out[idx] = (*status) ? cur[(((s << 4) + b) << 8) + d] : 20.0f;
}

__global__ __launch_bounds__(256) void k_fill(float* out, float v, int n) {
  int idx = blockIdx.x * 256 + threadIdx.x;
  if (idx < n) out[idx] = v;
}

extern "C" void kernel_launch(void* const* d_in, const int* in_sizes, int n_in,
                              void* d_out, int out_size, void* d_ws, size_t ws_size,
                              hipStream_t stream) {
  float* out = (float*)d_out;
  int fill_grid = (out_size + 255) / 256;

  const int exp_sizes[12] = {1048576, 4096, 16, 131072, 512, 131072, 512, 512,
                             524288, 512, 524288, 512};
  bool env_ok = (n_in == 12);
  if (env_ok)
    for (int i = 0; i < 12; ++i) env_ok = env_ok && (in_sizes[i] == exp_sizes[i]);
  if (!env_ok) {
    k_fill<<<fill_grid, 256, 0, stream>>>(out, 10.0f, out_size);
    return;
  }

  const float* x    = (const float*)d_in[0];
  const unsigned char* xmask = (const unsigned char*)d_in[1];
  const float* w1   = (const float*)d_in[3];
  const float* b1   = (const float*)d_in[4];
  const float* w2   = (const float*)d_in[5];
  const float* b2   = (const float*)d_in[6];
  const float* v    = (const float*)d_in[7];
  const float* sw_f = (const float*)d_in[8];
  const float* sb_f = (const float*)d_in[9];
  const float* sw_b = (const float*)d_in[10];
  const float* sb_b = (const float*)d_in[11];

  float* ws = (float*)d_ws;
  size_t off = 0;
  float* pb0    = ws + off; off += 1048576;
  float* pb1    = ws + off; off += 1048576;
  float* xt     = ws + off; off += 262144;
  float* scores = ws + off; off += 1048576;
  float* Uf     = ws + off; off += 2097152;
  float* Ub     = ws + off; off += 2097152;
  u16*   inp    = (u16*)(ws + off); off += 1048576;   // 2M u16
  u16*   wt     = (u16*)(ws + off); off += 524288;    // 1M u16
  int*   act    = (int*)(ws + off); off += 16;
  int*   status = (int*)(ws + off); off += 16;

  if (ws_size < off * sizeof(float)) {
    k_fill<<<fill_grid, 256, 0, stream>>>(out, 30.0f, out_size);
    return;
  }

  k_act<<<1, 64, 0, stream>>>((const int*)d_in[2], act, status);
  k_prep<<<dim3(8, 8, 4), 256, 0, stream>>>(sw_f, sw_b, wt);
  k_xt<<<dim3(4, 16), 256, 0, stream>>>(x, act, w1, b1, xt);

  for (int layer = 0; layer < 2; ++layer) {
    const float* curb = layer ? pb0 : x;
    int sstride = layer ? 4096 : 256;
    int bstride = layer ? 256 : 65536;
    float* nxt = layer ? pb1 : pb0;
    k_score<<<4096, 256, 0, stream>>>(xt, curb, sstride, bstride, w2, b2, v,
                                      act, xmask, scores);
    k_pool<<<dim3(4, 4, 16), 256, 0, stream>>>(scores, x, curb, sstride, bstride, inp);
    k_mfma<<<dim3(32, 4, 2), 256, 0, stream>>>(inp, wt, Uf, Ub, layer);
    k_scan<<<256, 256, 0, stream>>>(Uf, Ub, sb_f + layer * 256, sb_b + layer * 256, nxt);
  }
  k_out<<<4096, 256, 0, stream>>>(pb1, status, out);
}